// Round 12
// baseline (884.093 us; speedup 1.0000x reference)
//
#include <hip/hip_runtime.h>
#include <stdint.h>

typedef __bf16 bf16;
typedef unsigned char u8;
typedef __attribute__((ext_vector_type(8))) __bf16 bf16x8;
typedef __attribute__((ext_vector_type(4))) float f32x4;
typedef __attribute__((ext_vector_type(2))) float f32x2;

#define N_NODES 100000
#define F_IN 165
#define NB 391     // coarse buckets of 256 nodes
#define NBLK 320   // blocks in bucket passes
#define NSLICE 8
#define SLICE_F 16
#define SLICE_STRIDE ((size_t)(N_NODES + 1) * SLICE_F)  // bytes per fp8 slice

static inline int cdiv(int a, int b) { return (a + b - 1) / b; }

__device__ __forceinline__ float bfu(unsigned hw) {
  union { unsigned u; float f; } v; v.u = hw << 16; return v.f;
}
__device__ __forceinline__ unsigned packbf2(float a, float b) {
  bf16 x = (bf16)a, y = (bf16)b;
  unsigned short sx = __builtin_bit_cast(unsigned short, x);
  unsigned short sy = __builtin_bit_cast(unsigned short, y);
  return (unsigned)sx | ((unsigned)sy << 16);
}
__device__ __forceinline__ unsigned pk_fp8x4(float a, float b, float c, float d) {
  int v = 0;
  v = __builtin_amdgcn_cvt_pk_fp8_f32(a, b, v, false);
  v = __builtin_amdgcn_cvt_pk_fp8_f32(c, d, v, true);
  return (unsigned)v;
}
__device__ __forceinline__ u8 f32_to_fp8(float v) {
  int t = __builtin_amdgcn_cvt_pk_fp8_f32(v, 0.f, 0, false);
  return (u8)(t & 0xff);
}

__device__ __forceinline__ void async16(const bf16* g, const bf16* l) {
  __builtin_amdgcn_global_load_lds(
      (const __attribute__((address_space(1))) void*)g,
      (__attribute__((address_space(3))) void*)l, 16, 0, 0);
}

// ---------------- edge dtype detection ----------------
__global__ void detect_k(const int* __restrict__ ei32, int* __restrict__ flag) {
  int i = blockIdx.x * 256 + threadIdx.x;
  int v = ei32[2 * i + 1];
  if (v != 0) atomicOr(flag, 1);
}

// ---------------- bucket-sort preprocessing (LDS atomics only) ------

__global__ __launch_bounds__(256) void hist_k(const int* __restrict__ ei, int E,
                                              const int* __restrict__ flag,
                                              int* __restrict__ gcd, int* __restrict__ gcs) {
  __shared__ int hd[NB], hs[NB];
  int b = blockIdx.x, t = threadIdx.x;
  for (int i = t; i < NB; i += 256) { hd[i] = 0; hs[i] = 0; }
  __syncthreads();
  int sh = (*flag) ? 0 : 1;
  int CH = (E + NBLK - 1) / NBLK;
  int lo = b * CH, hi = min(E, lo + CH);
  for (int e = lo + t; e < hi; e += 256) {
    int s = ei[(size_t)e << sh];
    int d = ei[(size_t)(E + e) << sh];
    if ((unsigned)s < (unsigned)N_NODES && (unsigned)d < (unsigned)N_NODES && s != d) {
      atomicAdd(&hd[d >> 8], 1);
      atomicAdd(&hs[s >> 8], 1);
    }
  }
  __syncthreads();
  for (int i = t; i < NB; i += 256) {
    gcd[i * NBLK + b] = hd[i];
    gcs[i * NBLK + b] = hs[i];
  }
}

__global__ __launch_bounds__(256) void scat_dst_k(const int* __restrict__ ei, int E,
                                                  const int* __restrict__ flag,
                                                  const int* __restrict__ ofd,
                                                  unsigned* __restrict__ pk) {
  __shared__ int base[NB];
  int b = blockIdx.x, t = threadIdx.x;
  for (int i = t; i < NB; i += 256) base[i] = ofd[i * NBLK + b];
  __syncthreads();
  int sh = (*flag) ? 0 : 1;
  int CH = (E + NBLK - 1) / NBLK;
  int lo = b * CH, hi = min(E, lo + CH);
  for (int e = lo + t; e < hi; e += 256) {
    int s = ei[(size_t)e << sh];
    int d = ei[(size_t)(E + e) << sh];
    if ((unsigned)s < (unsigned)N_NODES && (unsigned)d < (unsigned)N_NODES && s != d) {
      int pos = atomicAdd(&base[d >> 8], 1);
      pk[pos] = ((unsigned)(d & 255) << 24) | (unsigned)s;
    }
  }
}

__global__ __launch_bounds__(256) void scat_src_k(const int* __restrict__ ei, int E,
                                                  const int* __restrict__ flag,
                                                  const int* __restrict__ ofs,
                                                  unsigned* __restrict__ pk2) {
  __shared__ int base[NB];
  int b = blockIdx.x, t = threadIdx.x;
  for (int i = t; i < NB; i += 256) base[i] = ofs[i * NBLK + b];
  __syncthreads();
  int sh = (*flag) ? 0 : 1;
  int CH = (E + NBLK - 1) / NBLK;
  int lo = b * CH, hi = min(E, lo + CH);
  for (int e = lo + t; e < hi; e += 256) {
    int s = ei[(size_t)e << sh];
    int d = ei[(size_t)(E + e) << sh];
    if ((unsigned)s < (unsigned)N_NODES && (unsigned)d < (unsigned)N_NODES && s != d) {
      int pos = atomicAdd(&base[s >> 8], 1);
      pk2[pos] = (unsigned)s;
    }
  }
}

__global__ __launch_bounds__(256) void fin_dst_k(const unsigned* __restrict__ pk,
                                                 const int* __restrict__ ofd,
                                                 const int* __restrict__ totald,
                                                 int* __restrict__ rowptr,
                                                 int* __restrict__ csr) {
  __shared__ int fh[256], fb[256];
  int b = blockIdx.x, t = threadIdx.x;
  int lo = ofd[b * NBLK];
  int hi = (b == NB - 1) ? *totald : ofd[(b + 1) * NBLK];
  fh[t] = 0;
  __syncthreads();
  for (int i = lo + t; i < hi; i += 256) atomicAdd(&fh[pk[i] >> 24], 1);
  __syncthreads();
  fb[t] = fh[t];
  __syncthreads();
  for (int offv = 1; offv < 256; offv <<= 1) {
    int x = (t >= offv) ? fb[t - offv] : 0;
    __syncthreads();
    fb[t] += x;
    __syncthreads();
  }
  int excl = fb[t] - fh[t];
  int node = b * 256 + t;
  if (node <= N_NODES) rowptr[node] = lo + excl;
  __syncthreads();
  fb[t] = lo + excl;
  __syncthreads();
  for (int i = lo + t; i < hi; i += 256) {
    unsigned v = pk[i];
    int pos = atomicAdd(&fb[v >> 24], 1);
    csr[pos] = (int)(v & 0xFFFFFFu);
  }
}

__global__ __launch_bounds__(256) void fin_src_k(const unsigned* __restrict__ pk2,
                                                 const int* __restrict__ ofs,
                                                 const int* __restrict__ totals,
                                                 float* __restrict__ dinv) {
  __shared__ int fh[256];
  int b = blockIdx.x, t = threadIdx.x;
  int lo = ofs[b * NBLK];
  int hi = (b == NB - 1) ? *totals : ofs[(b + 1) * NBLK];
  fh[t] = 0;
  __syncthreads();
  for (int i = lo + t; i < hi; i += 256) atomicAdd(&fh[pk2[i] & 255], 1);
  __syncthreads();
  int node = b * 256 + t;
  if (node < N_NODES) {
    int dg = fh[t];
    dinv[node] = dg > 0 ? rsqrtf((float)dg) : 0.f;
  }
}

// ---------------- scans ----------------

__global__ void scanA_k(const int* __restrict__ cnt, int* __restrict__ bsum, int nElem) {
  __shared__ int s[256];
  int b = blockIdx.x, t = threadIdx.x;
  int base = b * 1024;
  int sum = 0;
  for (int i = t; i < 1024; i += 256) {
    int idx = base + i;
    sum += (idx < nElem) ? cnt[idx] : 0;
  }
  s[t] = sum; __syncthreads();
  for (int off = 128; off > 0; off >>= 1) {
    if (t < off) s[t] += s[t + off];
    __syncthreads();
  }
  if (t == 0) bsum[b] = s[0];
}

__global__ void scanB_k(int* __restrict__ bsum, int* __restrict__ totalOut, int nChunk) {
  __shared__ int s[128];
  int t = threadIdx.x;
  int v = (t < nChunk) ? bsum[t] : 0;
  s[t] = v; __syncthreads();
  for (int off = 1; off < 128; off <<= 1) {
    int x = (t >= off) ? s[t - off] : 0;
    __syncthreads();
    s[t] += x;
    __syncthreads();
  }
  int excl = s[t] - v;
  if (t < nChunk) bsum[t] = excl;
  if (t == 127) *totalOut = s[127];
}

__global__ void scanC_k(const int* __restrict__ cnt, const int* __restrict__ bsum,
                        int* __restrict__ outp, int nElem) {
  __shared__ int s[256];
  int b = blockIdx.x, t = threadIdx.x;
  int base = b * 1024 + t * 4;
  int v[4]; int tot = 0;
  for (int i = 0; i < 4; i++) {
    int idx = base + i;
    v[i] = (idx < nElem) ? cnt[idx] : 0;
    tot += v[i];
  }
  s[t] = tot; __syncthreads();
  for (int off = 1; off < 256; off <<= 1) {
    int x = (t >= off) ? s[t - off] : 0;
    __syncthreads();
    s[t] += x;
    __syncthreads();
  }
  int excl = s[t] - tot + bsum[b];
  for (int i = 0; i < 4; i++) {
    int idx = base + i;
    if (idx < nElem) { outp[idx] = excl; excl += v[i]; }
  }
}

// ---------------- weight prep ----------------

__global__ void build_wct_k(const float* __restrict__ W, bf16* __restrict__ out, int Fin, int Kp) {
  int idx = blockIdx.x * 256 + threadIdx.x;
  if (idx >= 384 * Kp) return;
  int r = idx / Kp, k = idx % Kp;
  int t = r >> 7, j = r & 127;
  float v = 0.f;
  if (k < Fin) {
    if (t == 0)
      v = W[(size_t)k * 128 + j] - W[(size_t)2 * Fin * 128 + (size_t)k * 128 + j];
    else if (t == 1)
      v = W[(size_t)Fin * 128 + (size_t)k * 128 + j];
    else
      v = 2.f * W[(size_t)2 * Fin * 128 + (size_t)k * 128 + j];
  }
  out[(size_t)r * Kp + k] = (bf16)v;
}

__global__ void pad_x_k(const float* __restrict__ x, bf16* __restrict__ xp) {
  int idx = blockIdx.x * 256 + threadIdx.x;
  if (idx >= N_NODES * 192) return;
  int n = idx / 192, k = idx % 192;
  xp[idx] = (k < F_IN) ? (bf16)x[(size_t)n * F_IN + k] : (bf16)0.f;
}

// zero pad row (node N_NODES) of every slice in both fp8 buffers
__global__ void zero_pads_k(u8* __restrict__ g0, u8* __restrict__ g1) {
  int t = threadIdx.x;  // 128 threads: slice = t>>4, byte = t&15
  int s = t >> 4, byt = t & 15;
  g0[(size_t)s * SLICE_STRIDE + (size_t)N_NODES * 16 + byt] = 0;
  g1[(size_t)s * SLICE_STRIDE + (size_t)N_NODES * 16 + byt] = 0;
}

// ---------------- GEMM: y=0,1 -> bf16; y=2 -> fp8(dinv*val) SLICED layout ----

__global__ __launch_bounds__(256) void gemm3_k(const bf16* __restrict__ A, int lda,
                                               const bf16* __restrict__ Bt, int K,
                                               bf16* __restrict__ C0, bf16* __restrict__ C1,
                                               u8* __restrict__ C2g,
                                               const float* __restrict__ dinv, int M) {
  __shared__ __align__(16) bf16 As[128 * 32];
  __shared__ __align__(16) bf16 Bs[128 * 32];
  const int tid = threadIdx.x;
  const int w = tid >> 6, l = tid & 63;
  const int mBase = blockIdx.x * 128;
  const int nb = blockIdx.y * 128;
  const int wm = (w >> 1) * 64, wn = (w & 1) * 64;
  const int lr = l & 15, lq = l >> 4;
  f32x4 acc[4][4] = {};
  for (int k0 = 0; k0 < K; k0 += 32) {
#pragma unroll
    for (int p = 0; p < 2; ++p) {
      int q = w * 2 + p;
      int row = q * 16 + (l >> 2);
      int seg = (l & 3) * 8;
      int ar = mBase + row; if (ar > M - 1) ar = M - 1;
      async16(A + (size_t)ar * lda + k0 + seg, &As[q * 512]);
      async16(Bt + (size_t)(nb + row) * K + k0 + seg, &Bs[q * 512]);
    }
    __syncthreads();
    bf16x8 a[4], b[4];
#pragma unroll
    for (int i = 0; i < 4; i++) a[i] = *(const bf16x8*)&As[(wm + i * 16 + lr) * 32 + lq * 8];
#pragma unroll
    for (int j = 0; j < 4; j++) b[j] = *(const bf16x8*)&Bs[(wn + j * 16 + lr) * 32 + lq * 8];
#pragma unroll
    for (int i = 0; i < 4; i++)
#pragma unroll
      for (int j = 0; j < 4; j++)
        acc[i][j] = __builtin_amdgcn_mfma_f32_16x16x32_bf16(a[i], b[j], acc[i][j], 0, 0, 0);
    __syncthreads();
  }
  if (blockIdx.y == 2) {
#pragma unroll
    for (int i = 0; i < 4; i++) {
#pragma unroll
      for (int r = 0; r < 4; r++) {
        int row = mBase + wm + i * 16 + lq * 4 + r;
        if (row < M) {
          float dv = dinv[row];
#pragma unroll
          for (int j = 0; j < 4; j++) {
            int sc = (wn >> 4) + j;  // slice of col = wn + j*16 + lr
            C2g[(size_t)sc * SLICE_STRIDE + (size_t)row * 16 + lr] =
                f32_to_fp8(dv * acc[i][j][r]);
          }
        }
      }
    }
  } else {
    bf16* __restrict__ C = blockIdx.y ? C1 : C0;
#pragma unroll
    for (int i = 0; i < 4; i++) {
#pragma unroll
      for (int r = 0; r < 4; r++) {
        int row = mBase + wm + i * 16 + lq * 4 + r;
        if (row < M) {
#pragma unroll
          for (int j = 0; j < 4; j++) {
            int col = wn + j * 16 + lr;
            C[(size_t)row * 128 + col] = (bf16)acc[i][j][r];
          }
        }
      }
    }
  }
}

// ---------------- sparse propagation: XCD-sliced fp8 gather ----------------
// blockIdx & 7 = slice (XCD round-robin); block covers 16 nodes (4 waves x 4 nodes).
// Per wave: 4 nodes, 16 edge-slots each; lane gathers the full 16B slice per edge.
// MODE 0: t = -dn*sum + addA;  write fp8(dn*t) sliced -> out8
// MODE 1: t = relu(-dn*sum + addA + bias); write bf16 row-major -> outb
// MODE 2: zpart[s][n] = sum_f (-dn*sum_f) * Wl[f][:]   (extras in logits_k)
template <int MODE>
__global__ __launch_bounds__(256) void prop_k(const int* __restrict__ rowptr,
                                              const int* __restrict__ csr,
                                              const u8* __restrict__ g8,
                                              const float* __restrict__ dinv,
                                              const bf16* __restrict__ addA,
                                              const float* __restrict__ bias,
                                              const float* __restrict__ Wl,
                                              u8* __restrict__ out8,
                                              bf16* __restrict__ outb,
                                              f32x2* __restrict__ zpart) {
  const int bid = blockIdx.x;
  const int s = bid & 7;
  const int grp = bid >> 3;
  const int lane = threadIdx.x & 63;
  const int sub = lane >> 4, slot = lane & 15;
  const int n = grp * 16 + (threadIdx.x >> 6) * 4 + sub;
  const int beg = rowptr[n], end = rowptr[n + 1];
  const u8* __restrict__ gs = g8 + (size_t)s * SLICE_STRIDE;

  f32x2 acc[8] = {};
  for (int idx = beg + slot; idx < end; idx += 16) {
    int src = csr[idx];
    uint4 gv = *(const uint4*)(gs + (size_t)src * 16);
#pragma unroll
    for (int q = 0; q < 4; q++) {
      unsigned word = (q == 0) ? gv.x : (q == 1) ? gv.y : (q == 2) ? gv.z : gv.w;
      auto lo = __builtin_amdgcn_cvt_pk_f32_fp8((int)word, false);
      auto hi = __builtin_amdgcn_cvt_pk_f32_fp8((int)word, true);
      acc[2 * q].x += lo[0];
      acc[2 * q].y += lo[1];
      acc[2 * q + 1].x += hi[0];
      acc[2 * q + 1].y += hi[1];
    }
  }
  // reduce 16 slots -> slot 0 (within each 16-lane group)
#pragma unroll
  for (int off = 8; off >= 1; off >>= 1) {
#pragma unroll
    for (int i = 0; i < 8; i++) {
      acc[i].x += __shfl_down(acc[i].x, off);
      acc[i].y += __shfl_down(acc[i].y, off);
    }
  }
  if (slot != 0) return;
  const float dn = dinv[n];
  float tv[16];
#pragma unroll
  for (int i = 0; i < 8; i++) {
    tv[2 * i] = -dn * acc[i].x;
    tv[2 * i + 1] = -dn * acc[i].y;
  }

  if (MODE == 2) {
    float zp0 = 0.f, zp1 = 0.f;
#pragma unroll
    for (int i = 0; i < 16; i++) {
      int f = s * 16 + i;
      zp0 += tv[i] * Wl[f * 2];
      zp1 += tv[i] * Wl[f * 2 + 1];
    }
    f32x2 zp; zp.x = zp0; zp.y = zp1;
    zpart[(size_t)s * N_NODES + n] = zp;
  } else {
    const uint2* ap = (const uint2*)(addA + (size_t)n * 128 + s * 16);
#pragma unroll
    for (int i = 0; i < 4; i++) {
      uint2 u = ap[i];
      tv[4 * i + 0] += bfu(u.x & 0xffffu);
      tv[4 * i + 1] += bfu(u.x >> 16);
      tv[4 * i + 2] += bfu(u.y & 0xffffu);
      tv[4 * i + 3] += bfu(u.y >> 16);
    }
    if (MODE == 1) {
#pragma unroll
      for (int i = 0; i < 16; i++) tv[i] = fmaxf(tv[i] + bias[s * 16 + i], 0.f);
      uint4 s0, s1;
      s0.x = packbf2(tv[0], tv[1]);  s0.y = packbf2(tv[2], tv[3]);
      s0.z = packbf2(tv[4], tv[5]);  s0.w = packbf2(tv[6], tv[7]);
      s1.x = packbf2(tv[8], tv[9]);  s1.y = packbf2(tv[10], tv[11]);
      s1.z = packbf2(tv[12], tv[13]); s1.w = packbf2(tv[14], tv[15]);
      uint4* op = (uint4*)(outb + (size_t)n * 128 + s * 16);
      op[0] = s0; op[1] = s1;
    } else {
      uint4 st;
      st.x = pk_fp8x4(dn * tv[0], dn * tv[1], dn * tv[2], dn * tv[3]);
      st.y = pk_fp8x4(dn * tv[4], dn * tv[5], dn * tv[6], dn * tv[7]);
      st.z = pk_fp8x4(dn * tv[8], dn * tv[9], dn * tv[10], dn * tv[11]);
      st.w = pk_fp8x4(dn * tv[12], dn * tv[13], dn * tv[14], dn * tv[15]);
      *(uint4*)(out8 + (size_t)s * SLICE_STRIDE + (size_t)n * 16) = st;
    }
  }
}

// final: logits = log_softmax((extras @ Wl) + sum_s zpart + bl), extras = Z0+h+b2
__global__ __launch_bounds__(256) void logits_k(const bf16* __restrict__ addA,
                                                const bf16* __restrict__ addB,
                                                const float* __restrict__ bias,
                                                const float* __restrict__ Wl,
                                                const float* __restrict__ bl,
                                                const f32x2* __restrict__ zpart,
                                                float* __restrict__ fout) {
  int n = blockIdx.x * 4 + (threadIdx.x >> 6);
  int c = threadIdx.x & 63;
  unsigned ua = *(const unsigned*)(addA + (size_t)n * 128 + 2 * c);
  unsigned uh = *(const unsigned*)(addB + (size_t)n * 128 + 2 * c);
  float t0 = bfu(ua & 0xffffu) + bfu(uh & 0xffffu) + bias[2 * c];
  float t1 = bfu(ua >> 16) + bfu(uh >> 16) + bias[2 * c + 1];
  float z0 = t0 * Wl[(2 * c) * 2] + t1 * Wl[(2 * c + 1) * 2];
  float z1 = t0 * Wl[(2 * c) * 2 + 1] + t1 * Wl[(2 * c + 1) * 2 + 1];
  if (c < 8) {
    f32x2 zp = zpart[(size_t)c * N_NODES + n];
    z0 += zp.x;
    z1 += zp.y;
  }
#pragma unroll
  for (int off = 32; off > 0; off >>= 1) {
    z0 += __shfl_down(z0, off);
    z1 += __shfl_down(z1, off);
  }
  if (c == 0) {
    z0 += bl[0];
    z1 += bl[1];
    float m = fmaxf(z0, z1);
    float lse = m + logf(expf(z0 - m) + expf(z1 - m));
    fout[(size_t)n * 2 + 0] = z0 - lse;
    fout[(size_t)n * 2 + 1] = z1 - lse;
  }
}

// edges -> float32 output region
__global__ void copy_edges_k(const int* __restrict__ ei, const int* __restrict__ flag,
                             float* __restrict__ out, int n) {
  int i = blockIdx.x * 256 + threadIdx.x;
  if (i >= n) return;
  int sh = (*flag) ? 0 : 1;
  out[i] = (float)ei[(size_t)i << sh];
}

// ---------------- launch ----------------

extern "C" void kernel_launch(void* const* d_in, const int* in_sizes, int n_in,
                              void* d_out, int out_size, void* d_ws, size_t ws_size,
                              hipStream_t stream) {
  const float* x = (const float*)d_in[0];
  const int* ei = (const int*)d_in[1];
  const float* W1 = (const float*)d_in[2];
  const float* b1 = (const float*)d_in[3];
  const float* W2 = (const float*)d_in[4];
  const float* b2 = (const float*)d_in[5];
  const float* Wl = (const float*)d_in[6];
  const float* bl = (const float*)d_in[7];
  float* outp = (float*)d_out;

  const int N = N_NODES;
  const int E = in_sizes[1] / 2;
  const int L = NB * NBLK;
  const int nChunkS = cdiv(L, 1024);

  char* ws = (char*)d_ws;
  size_t off = 0;
  auto alloc = [&](size_t bytes) {
    off = (off + 255) & ~(size_t)255;
    size_t o = off;
    off += bytes;
    return o;
  };
  int* flag = (int*)(ws + alloc(4));
  int* gcd = (int*)(ws + alloc((size_t)L * 4));
  int* gcs = (int*)(ws + alloc((size_t)L * 4));
  int* bsum = (int*)(ws + alloc(512));
  int* totald = (int*)(ws + alloc(4));
  int* totals = (int*)(ws + alloc(4));
  int* rowptr = (int*)(ws + alloc((size_t)(N + 1) * 4));
  float* dinv = (float*)(ws + alloc((size_t)N * 4));
  unsigned* pk = (unsigned*)(ws + alloc((size_t)E * 4));
  unsigned* pk2 = (unsigned*)(ws + alloc((size_t)E * 4));
  int* csr = (int*)(ws + alloc((size_t)E * 4));
  bf16* wct1 = (bf16*)(ws + alloc((size_t)384 * 192 * 2));
  bf16* wct2 = (bf16*)(ws + alloc((size_t)384 * 128 * 2));
  bf16* xp = (bf16*)(ws + alloc((size_t)N * 192 * 2));
  bf16* H = xp;  // h reuses xp (dead after gemm1)
  bf16* U0 = (bf16*)(ws + alloc((size_t)N * 128 * 2));
  bf16* U1 = (bf16*)(ws + alloc((size_t)N * 128 * 2));
  u8* G0 = (u8*)(ws + alloc((size_t)NSLICE * SLICE_STRIDE));
  u8* G1 = (u8*)(ws + alloc((size_t)NSLICE * SLICE_STRIDE));
  f32x2* zpart = (f32x2*)(ws + alloc((size_t)NSLICE * N * 8));
  (void)ws_size;  // total ~ 147 MB

  hipMemsetAsync(flag, 0, 4, stream);
  detect_k<<<256, 256, 0, stream>>>(ei, flag);

  // ---- bucket-sort CSR + degree ----
  hist_k<<<NBLK, 256, 0, stream>>>(ei, E, flag, gcd, gcs);
  scanA_k<<<nChunkS, 256, 0, stream>>>(gcd, bsum, L);
  scanB_k<<<1, 128, 0, stream>>>(bsum, totald, nChunkS);
  scanC_k<<<nChunkS, 256, 0, stream>>>(gcd, bsum, gcd, L);
  scanA_k<<<nChunkS, 256, 0, stream>>>(gcs, bsum, L);
  scanB_k<<<1, 128, 0, stream>>>(bsum, totals, nChunkS);
  scanC_k<<<nChunkS, 256, 0, stream>>>(gcs, bsum, gcs, L);
  scat_dst_k<<<NBLK, 256, 0, stream>>>(ei, E, flag, gcd, pk);
  scat_src_k<<<NBLK, 256, 0, stream>>>(ei, E, flag, gcs, pk2);
  fin_dst_k<<<NB, 256, 0, stream>>>(pk, gcd, totald, rowptr, csr);
  fin_src_k<<<NB, 256, 0, stream>>>(pk2, gcs, totals, dinv);

  zero_pads_k<<<1, 128, 0, stream>>>(G0, G1);
  pad_x_k<<<cdiv(N * 192, 256), 256, 0, stream>>>(x, xp);
  build_wct_k<<<cdiv(384 * 192, 256), 256, 0, stream>>>(W1, wct1, F_IN, 192);
  build_wct_k<<<cdiv(384 * 128, 256), 256, 0, stream>>>(W2, wct2, 128, 128);

  const int gm = cdiv(N, 128);
  const int pgrid = (N / 16) * NSLICE;  // 50000 blocks
  // layer 1: Y0 -> U0 (bf16), Y1 -> U1 (bf16), Y2 -> G0 (fp8 sliced, dinv-scaled)
  gemm3_k<<<dim3(gm, 3), 256, 0, stream>>>(xp, 192, wct1, 192, U0, U1, G0, dinv, N);
  // A1 sliced fp8 = dinv*(P(Y2)+Y1): gather G0, add U1 -> G1
  prop_k<0><<<pgrid, 256, 0, stream>>>(rowptr, csr, G0, dinv, U1, nullptr, nullptr,
                                       G1, nullptr, nullptr);
  // h = relu(P(A1)+Y0+b1): gather G1, add U0 -> H (bf16 row-major)
  prop_k<1><<<pgrid, 256, 0, stream>>>(rowptr, csr, G1, dinv, U0, b1, nullptr,
                                       nullptr, H, nullptr);
  // layer 2 from h: Z0 -> U1, Z1 -> U0, Z2 -> G0 (fp8 sliced)
  gemm3_k<<<dim3(gm, 3), 256, 0, stream>>>(H, 128, wct2, 128, U1, U0, G0, dinv, N);
  // A2 sliced fp8 = dinv*(P(Z2)+Z1): gather G0, add U0 -> G1
  prop_k<0><<<pgrid, 256, 0, stream>>>(rowptr, csr, G0, dinv, U0, nullptr, nullptr,
                                       G1, nullptr, nullptr);
  // zpart[s][n] from gather of G1
  prop_k<2><<<pgrid, 256, 0, stream>>>(rowptr, csr, G1, dinv, nullptr, nullptr, Wl,
                                       nullptr, nullptr, zpart);
  // logits = log_softmax((Z0+h+b2)@Wl + sum zpart + bl)
  logits_k<<<N / 4, 256, 0, stream>>>(U1, H, b2, Wl, bl, zpart, outp);

  copy_edges_k<<<cdiv(2 * E, 256), 256, 0, stream>>>(ei, flag, outp + (size_t)2 * N, 2 * E);
}

// Round 13
// 859.594 us; speedup vs baseline: 1.0285x; 1.0285x over previous
//
#include <hip/hip_runtime.h>
#include <stdint.h>

typedef __bf16 bf16;
typedef unsigned char u8;
typedef __attribute__((ext_vector_type(8))) __bf16 bf16x8;
typedef __attribute__((ext_vector_type(4))) float f32x4;
typedef __attribute__((ext_vector_type(2))) float f32x2;

#define N_NODES 100000
#define F_IN 165
#define NB 391     // coarse buckets of 256 nodes
#define NBLK 320   // blocks in bucket passes
#define NSLICE 4
#define SLICE_STRIDE ((size_t)(N_NODES + 1) * 32)  // bytes per 32-feature fp8 slice

static inline int cdiv(int a, int b) { return (a + b - 1) / b; }

__device__ __forceinline__ float bfu(unsigned hw) {
  union { unsigned u; float f; } v; v.u = hw << 16; return v.f;
}
__device__ __forceinline__ unsigned packbf2(float a, float b) {
  bf16 x = (bf16)a, y = (bf16)b;
  unsigned short sx = __builtin_bit_cast(unsigned short, x);
  unsigned short sy = __builtin_bit_cast(unsigned short, y);
  return (unsigned)sx | ((unsigned)sy << 16);
}
__device__ __forceinline__ unsigned pk_fp8x4(float a, float b, float c, float d) {
  int v = 0;
  v = __builtin_amdgcn_cvt_pk_fp8_f32(a, b, v, false);
  v = __builtin_amdgcn_cvt_pk_fp8_f32(c, d, v, true);
  return (unsigned)v;
}
__device__ __forceinline__ u8 f32_to_fp8(float v) {
  int t = __builtin_amdgcn_cvt_pk_fp8_f32(v, 0.f, 0, false);
  return (u8)(t & 0xff);
}

__device__ __forceinline__ void async16(const bf16* g, const bf16* l) {
  __builtin_amdgcn_global_load_lds(
      (const __attribute__((address_space(1))) void*)g,
      (__attribute__((address_space(3))) void*)l, 16, 0, 0);
}

// ---------------- edge dtype detection ----------------
__global__ void detect_k(const int* __restrict__ ei32, int* __restrict__ flag) {
  int i = blockIdx.x * 256 + threadIdx.x;
  int v = ei32[2 * i + 1];
  if (v != 0) atomicOr(flag, 1);
}

// ---------------- bucket-sort preprocessing (LDS atomics only) ------

__global__ __launch_bounds__(256) void hist_k(const int* __restrict__ ei, int E,
                                              const int* __restrict__ flag,
                                              int* __restrict__ gcd, int* __restrict__ gcs) {
  __shared__ int hd[NB], hs[NB];
  int b = blockIdx.x, t = threadIdx.x;
  for (int i = t; i < NB; i += 256) { hd[i] = 0; hs[i] = 0; }
  __syncthreads();
  int sh = (*flag) ? 0 : 1;
  int CH = (E + NBLK - 1) / NBLK;
  int lo = b * CH, hi = min(E, lo + CH);
  for (int e = lo + t; e < hi; e += 256) {
    int s = ei[(size_t)e << sh];
    int d = ei[(size_t)(E + e) << sh];
    if ((unsigned)s < (unsigned)N_NODES && (unsigned)d < (unsigned)N_NODES && s != d) {
      atomicAdd(&hd[d >> 8], 1);
      atomicAdd(&hs[s >> 8], 1);
    }
  }
  __syncthreads();
  for (int i = t; i < NB; i += 256) {
    gcd[i * NBLK + b] = hd[i];
    gcs[i * NBLK + b] = hs[i];
  }
}

// fused: scatter packed dst-sorted and src-sorted arrays in one edge pass
__global__ __launch_bounds__(256) void scat2_k(const int* __restrict__ ei, int E,
                                               const int* __restrict__ flag,
                                               const int* __restrict__ ofd,
                                               const int* __restrict__ ofs,
                                               unsigned* __restrict__ pk,
                                               unsigned* __restrict__ pk2) {
  __shared__ int based[NB], bases[NB];
  int b = blockIdx.x, t = threadIdx.x;
  for (int i = t; i < NB; i += 256) {
    based[i] = ofd[i * NBLK + b];
    bases[i] = ofs[i * NBLK + b];
  }
  __syncthreads();
  int sh = (*flag) ? 0 : 1;
  int CH = (E + NBLK - 1) / NBLK;
  int lo = b * CH, hi = min(E, lo + CH);
  for (int e = lo + t; e < hi; e += 256) {
    int s = ei[(size_t)e << sh];
    int d = ei[(size_t)(E + e) << sh];
    if ((unsigned)s < (unsigned)N_NODES && (unsigned)d < (unsigned)N_NODES && s != d) {
      int pd = atomicAdd(&based[d >> 8], 1);
      pk[pd] = ((unsigned)(d & 255) << 24) | (unsigned)s;
      int ps = atomicAdd(&bases[s >> 8], 1);
      pk2[ps] = (unsigned)s;
    }
  }
}

__global__ __launch_bounds__(256) void fin_dst_k(const unsigned* __restrict__ pk,
                                                 const int* __restrict__ ofd,
                                                 const int* __restrict__ totald,
                                                 int* __restrict__ rowptr,
                                                 int* __restrict__ csr) {
  __shared__ int fh[256], fb[256];
  int b = blockIdx.x, t = threadIdx.x;
  int lo = ofd[b * NBLK];
  int hi = (b == NB - 1) ? *totald : ofd[(b + 1) * NBLK];
  fh[t] = 0;
  __syncthreads();
  for (int i = lo + t; i < hi; i += 256) atomicAdd(&fh[pk[i] >> 24], 1);
  __syncthreads();
  fb[t] = fh[t];
  __syncthreads();
  for (int offv = 1; offv < 256; offv <<= 1) {
    int x = (t >= offv) ? fb[t - offv] : 0;
    __syncthreads();
    fb[t] += x;
    __syncthreads();
  }
  int excl = fb[t] - fh[t];
  int node = b * 256 + t;
  if (node <= N_NODES) rowptr[node] = lo + excl;
  __syncthreads();
  fb[t] = lo + excl;
  __syncthreads();
  for (int i = lo + t; i < hi; i += 256) {
    unsigned v = pk[i];
    int pos = atomicAdd(&fb[v >> 24], 1);
    csr[pos] = (int)(v & 0xFFFFFFu);
  }
}

__global__ __launch_bounds__(256) void fin_src_k(const unsigned* __restrict__ pk2,
                                                 const int* __restrict__ ofs,
                                                 const int* __restrict__ totals,
                                                 float* __restrict__ dinv) {
  __shared__ int fh[256];
  int b = blockIdx.x, t = threadIdx.x;
  int lo = ofs[b * NBLK];
  int hi = (b == NB - 1) ? *totals : ofs[(b + 1) * NBLK];
  fh[t] = 0;
  __syncthreads();
  for (int i = lo + t; i < hi; i += 256) atomicAdd(&fh[pk2[i] & 255], 1);
  __syncthreads();
  int node = b * 256 + t;
  if (node < N_NODES) {
    int dg = fh[t];
    dinv[node] = dg > 0 ? rsqrtf((float)dg) : 0.f;
  }
}

// ---------------- scans ----------------

__global__ void scanA_k(const int* __restrict__ cnt, int* __restrict__ bsum, int nElem) {
  __shared__ int s[256];
  int b = blockIdx.x, t = threadIdx.x;
  int base = b * 1024;
  int sum = 0;
  for (int i = t; i < 1024; i += 256) {
    int idx = base + i;
    sum += (idx < nElem) ? cnt[idx] : 0;
  }
  s[t] = sum; __syncthreads();
  for (int off = 128; off > 0; off >>= 1) {
    if (t < off) s[t] += s[t + off];
    __syncthreads();
  }
  if (t == 0) bsum[b] = s[0];
}

__global__ void scanB_k(int* __restrict__ bsum, int* __restrict__ totalOut, int nChunk) {
  __shared__ int s[128];
  int t = threadIdx.x;
  int v = (t < nChunk) ? bsum[t] : 0;
  s[t] = v; __syncthreads();
  for (int off = 1; off < 128; off <<= 1) {
    int x = (t >= off) ? s[t - off] : 0;
    __syncthreads();
    s[t] += x;
    __syncthreads();
  }
  int excl = s[t] - v;
  if (t < nChunk) bsum[t] = excl;
  if (t == 127) *totalOut = s[127];
}

__global__ void scanC_k(const int* __restrict__ cnt, const int* __restrict__ bsum,
                        int* __restrict__ outp, int nElem) {
  __shared__ int s[256];
  int b = blockIdx.x, t = threadIdx.x;
  int base = b * 1024 + t * 4;
  int v[4]; int tot = 0;
  for (int i = 0; i < 4; i++) {
    int idx = base + i;
    v[i] = (idx < nElem) ? cnt[idx] : 0;
    tot += v[i];
  }
  s[t] = tot; __syncthreads();
  for (int off = 1; off < 256; off <<= 1) {
    int x = (t >= off) ? s[t - off] : 0;
    __syncthreads();
    s[t] += x;
    __syncthreads();
  }
  int excl = s[t] - tot + bsum[b];
  for (int i = 0; i < 4; i++) {
    int idx = base + i;
    if (idx < nElem) { outp[idx] = excl; excl += v[i]; }
  }
}

// ---------------- weight prep ----------------

__global__ void build_wct_k(const float* __restrict__ W, bf16* __restrict__ out, int Fin, int Kp) {
  int idx = blockIdx.x * 256 + threadIdx.x;
  if (idx >= 384 * Kp) return;
  int r = idx / Kp, k = idx % Kp;
  int t = r >> 7, j = r & 127;
  float v = 0.f;
  if (k < Fin) {
    if (t == 0)
      v = W[(size_t)k * 128 + j] - W[(size_t)2 * Fin * 128 + (size_t)k * 128 + j];
    else if (t == 1)
      v = W[(size_t)Fin * 128 + (size_t)k * 128 + j];
    else
      v = 2.f * W[(size_t)2 * Fin * 128 + (size_t)k * 128 + j];
  }
  out[(size_t)r * Kp + k] = (bf16)v;
}

__global__ void pad_x_k(const float* __restrict__ x, bf16* __restrict__ xp) {
  int idx = blockIdx.x * 256 + threadIdx.x;
  if (idx >= N_NODES * 192) return;
  int n = idx / 192, k = idx % 192;
  xp[idx] = (k < F_IN) ? (bf16)x[(size_t)n * F_IN + k] : (bf16)0.f;
}

// zero pad row (node N_NODES) of every slice in both fp8 buffers
__global__ void zero_pads_k(u8* __restrict__ g0, u8* __restrict__ g1) {
  int t = threadIdx.x;  // 256 threads: buf = t>>7, slice = (t>>5)&3, byte = t&31
  u8* g = (t >> 7) ? g1 : g0;
  int s = (t >> 5) & 3, byt = t & 31;
  g[(size_t)s * SLICE_STRIDE + (size_t)N_NODES * 32 + byt] = 0;
}

// ---------------- GEMM: y=0,1 -> bf16; y=2 -> fp8(dinv*val) 4-slice layout ----

__global__ __launch_bounds__(256) void gemm3_k(const bf16* __restrict__ A, int lda,
                                               const bf16* __restrict__ Bt, int K,
                                               bf16* __restrict__ C0, bf16* __restrict__ C1,
                                               u8* __restrict__ C2g,
                                               const float* __restrict__ dinv, int M) {
  __shared__ __align__(16) bf16 As[128 * 32];
  __shared__ __align__(16) bf16 Bs[128 * 32];
  const int tid = threadIdx.x;
  const int w = tid >> 6, l = tid & 63;
  const int mBase = blockIdx.x * 128;
  const int nb = blockIdx.y * 128;
  const int wm = (w >> 1) * 64, wn = (w & 1) * 64;
  const int lr = l & 15, lq = l >> 4;
  f32x4 acc[4][4] = {};
  for (int k0 = 0; k0 < K; k0 += 32) {
#pragma unroll
    for (int p = 0; p < 2; ++p) {
      int q = w * 2 + p;
      int row = q * 16 + (l >> 2);
      int seg = (l & 3) * 8;
      int ar = mBase + row; if (ar > M - 1) ar = M - 1;
      async16(A + (size_t)ar * lda + k0 + seg, &As[q * 512]);
      async16(Bt + (size_t)(nb + row) * K + k0 + seg, &Bs[q * 512]);
    }
    __syncthreads();
    bf16x8 a[4], b[4];
#pragma unroll
    for (int i = 0; i < 4; i++) a[i] = *(const bf16x8*)&As[(wm + i * 16 + lr) * 32 + lq * 8];
#pragma unroll
    for (int j = 0; j < 4; j++) b[j] = *(const bf16x8*)&Bs[(wn + j * 16 + lr) * 32 + lq * 8];
#pragma unroll
    for (int i = 0; i < 4; i++)
#pragma unroll
      for (int j = 0; j < 4; j++)
        acc[i][j] = __builtin_amdgcn_mfma_f32_16x16x32_bf16(a[i], b[j], acc[i][j], 0, 0, 0);
    __syncthreads();
  }
  if (blockIdx.y == 2) {
#pragma unroll
    for (int i = 0; i < 4; i++) {
#pragma unroll
      for (int r = 0; r < 4; r++) {
        int row = mBase + wm + i * 16 + lq * 4 + r;
        if (row < M) {
          float dv = dinv[row];
#pragma unroll
          for (int j = 0; j < 4; j++) {
            int colbase = wn + j * 16;          // lr stays within the slice
            int sc = colbase >> 5;
            int co = (colbase & 31) + lr;
            C2g[(size_t)sc * SLICE_STRIDE + (size_t)row * 32 + co] =
                f32_to_fp8(dv * acc[i][j][r]);
          }
        }
      }
    }
  } else {
    bf16* __restrict__ C = blockIdx.y ? C1 : C0;
#pragma unroll
    for (int i = 0; i < 4; i++) {
#pragma unroll
      for (int r = 0; r < 4; r++) {
        int row = mBase + wm + i * 16 + lq * 4 + r;
        if (row < M) {
#pragma unroll
          for (int j = 0; j < 4; j++) {
            int col = wn + j * 16 + lr;
            C[(size_t)row * 128 + col] = (bf16)acc[i][j][r];
          }
        }
      }
    }
  }
}

// ---------------- sparse propagation: 4-slice XCD-resident fp8 gather --------
// bid = g*4 + s; slice s = bid&3 (constant per XCD under round-robin mapping).
// Wave = 1 node: 8 lanes per edge (lane j covers features s*32 + j*4 ..+3),
// 16 edge-slots per iteration (2 gathers/lane). End: one 3-level shuffle.
// MODE 0: t = -dn*sum + addA;  write fp8(dn*t) sliced -> out8
// MODE 1: t = relu(-dn*sum + addA + bias); write bf16 row-major -> outb
// MODE 2: zpart[s][n] = sum_f t_f * Wl[f][:]  (extras folded in logits_k)
template <int MODE>
__global__ __launch_bounds__(256) void prop_k(const int* __restrict__ rowptr,
                                              const int* __restrict__ csr,
                                              const u8* __restrict__ g8,
                                              const float* __restrict__ dinv,
                                              const bf16* __restrict__ addA,
                                              const float* __restrict__ bias,
                                              const float* __restrict__ Wl,
                                              u8* __restrict__ out8,
                                              bf16* __restrict__ outb,
                                              f32x2* __restrict__ zpart) {
  const int bid = blockIdx.x;
  const int s = bid & 3;
  const int g = bid >> 2;
  const int n = g * 4 + (threadIdx.x >> 6);
  const int lane = threadIdx.x & 63;
  const int slot = lane >> 3, j = lane & 7;
  const int beg = rowptr[n], end = rowptr[n + 1];
  const u8* __restrict__ gs = g8 + (size_t)s * SLICE_STRIDE + j * 4;

  float a0 = 0.f, a1 = 0.f, a2 = 0.f, a3 = 0.f;
  for (int e0 = beg; e0 < end; e0 += 16) {
    int i0 = e0 + slot, i1 = e0 + 8 + slot;
    int s0 = (i0 < end) ? csr[i0] : N_NODES;
    int s1 = (i1 < end) ? csr[i1] : N_NODES;
    unsigned g0 = *(const unsigned*)(gs + (size_t)s0 * 32);
    unsigned g1 = *(const unsigned*)(gs + (size_t)s1 * 32);
    auto l0 = __builtin_amdgcn_cvt_pk_f32_fp8((int)g0, false);
    auto h0 = __builtin_amdgcn_cvt_pk_f32_fp8((int)g0, true);
    auto l1 = __builtin_amdgcn_cvt_pk_f32_fp8((int)g1, false);
    auto h1 = __builtin_amdgcn_cvt_pk_f32_fp8((int)g1, true);
    a0 += l0[0] + l1[0];
    a1 += l0[1] + l1[1];
    a2 += h0[0] + h1[0];
    a3 += h0[1] + h1[1];
  }
  // reduce across the 8 slots (lanes with same j): offs 32,16,8
#pragma unroll
  for (int off = 32; off >= 8; off >>= 1) {
    a0 += __shfl_down(a0, off);
    a1 += __shfl_down(a1, off);
    a2 += __shfl_down(a2, off);
    a3 += __shfl_down(a3, off);
  }
  if (slot != 0) return;  // lanes 0..7 remain; lane index == j
  const float dn = dinv[n];
  float t0 = -dn * a0, t1 = -dn * a1, t2 = -dn * a2, t3 = -dn * a3;
  const int f = s * 32 + j * 4;

  if (MODE == 2) {
    float z0 = t0 * Wl[f * 2] + t1 * Wl[(f + 1) * 2] + t2 * Wl[(f + 2) * 2] +
               t3 * Wl[(f + 3) * 2];
    float z1 = t0 * Wl[f * 2 + 1] + t1 * Wl[(f + 1) * 2 + 1] + t2 * Wl[(f + 2) * 2 + 1] +
               t3 * Wl[(f + 3) * 2 + 1];
#pragma unroll
    for (int off = 4; off >= 1; off >>= 1) {
      z0 += __shfl_down(z0, off);
      z1 += __shfl_down(z1, off);
    }
    if (j == 0) {
      f32x2 zp; zp.x = z0; zp.y = z1;
      zpart[(size_t)s * N_NODES + n] = zp;
    }
  } else {
    uint2 u = *(const uint2*)(addA + (size_t)n * 128 + f);
    t0 += bfu(u.x & 0xffffu);
    t1 += bfu(u.x >> 16);
    t2 += bfu(u.y & 0xffffu);
    t3 += bfu(u.y >> 16);
    if (MODE == 1) {
      t0 = fmaxf(t0 + bias[f], 0.f);
      t1 = fmaxf(t1 + bias[f + 1], 0.f);
      t2 = fmaxf(t2 + bias[f + 2], 0.f);
      t3 = fmaxf(t3 + bias[f + 3], 0.f);
      uint2 st;
      st.x = packbf2(t0, t1);
      st.y = packbf2(t2, t3);
      *(uint2*)(outb + (size_t)n * 128 + f) = st;
    } else {
      *(unsigned*)(out8 + (size_t)s * SLICE_STRIDE + (size_t)n * 32 + j * 4) =
          pk_fp8x4(dn * t0, dn * t1, dn * t2, dn * t3);
    }
  }
}

// final: logits = log_softmax((Z0+h+b2) @ Wl + sum_s zpart + bl)
__global__ __launch_bounds__(256) void logits_k(const bf16* __restrict__ addA,
                                                const bf16* __restrict__ addB,
                                                const float* __restrict__ bias,
                                                const float* __restrict__ Wl,
                                                const float* __restrict__ bl,
                                                const f32x2* __restrict__ zpart,
                                                float* __restrict__ fout) {
  int n = blockIdx.x * 4 + (threadIdx.x >> 6);
  int c = threadIdx.x & 63;
  unsigned ua = *(const unsigned*)(addA + (size_t)n * 128 + 2 * c);
  unsigned uh = *(const unsigned*)(addB + (size_t)n * 128 + 2 * c);
  float t0 = bfu(ua & 0xffffu) + bfu(uh & 0xffffu) + bias[2 * c];
  float t1 = bfu(ua >> 16) + bfu(uh >> 16) + bias[2 * c + 1];
  float z0 = t0 * Wl[(2 * c) * 2] + t1 * Wl[(2 * c + 1) * 2];
  float z1 = t0 * Wl[(2 * c) * 2 + 1] + t1 * Wl[(2 * c + 1) * 2 + 1];
  if (c < NSLICE) {
    f32x2 zp = zpart[(size_t)c * N_NODES + n];
    z0 += zp.x;
    z1 += zp.y;
  }
#pragma unroll
  for (int off = 32; off > 0; off >>= 1) {
    z0 += __shfl_down(z0, off);
    z1 += __shfl_down(z1, off);
  }
  if (c == 0) {
    z0 += bl[0];
    z1 += bl[1];
    float m = fmaxf(z0, z1);
    float lse = m + logf(expf(z0 - m) + expf(z1 - m));
    fout[(size_t)n * 2 + 0] = z0 - lse;
    fout[(size_t)n * 2 + 1] = z1 - lse;
  }
}

// edges -> float32 output region
__global__ void copy_edges_k(const int* __restrict__ ei, const int* __restrict__ flag,
                             float* __restrict__ out, int n) {
  int i = blockIdx.x * 256 + threadIdx.x;
  if (i >= n) return;
  int sh = (*flag) ? 0 : 1;
  out[i] = (float)ei[(size_t)i << sh];
}

// ---------------- launch ----------------

extern "C" void kernel_launch(void* const* d_in, const int* in_sizes, int n_in,
                              void* d_out, int out_size, void* d_ws, size_t ws_size,
                              hipStream_t stream) {
  const float* x = (const float*)d_in[0];
  const int* ei = (const int*)d_in[1];
  const float* W1 = (const float*)d_in[2];
  const float* b1 = (const float*)d_in[3];
  const float* W2 = (const float*)d_in[4];
  const float* b2 = (const float*)d_in[5];
  const float* Wl = (const float*)d_in[6];
  const float* bl = (const float*)d_in[7];
  float* outp = (float*)d_out;

  const int N = N_NODES;
  const int E = in_sizes[1] / 2;
  const int L = NB * NBLK;
  const int nChunkS = cdiv(L, 1024);

  char* ws = (char*)d_ws;
  size_t off = 0;
  auto alloc = [&](size_t bytes) {
    off = (off + 255) & ~(size_t)255;
    size_t o = off;
    off += bytes;
    return o;
  };
  int* flag = (int*)(ws + alloc(4));
  int* gcd = (int*)(ws + alloc((size_t)L * 4));
  int* gcs = (int*)(ws + alloc((size_t)L * 4));
  int* bsum = (int*)(ws + alloc(512));
  int* totald = (int*)(ws + alloc(4));
  int* totals = (int*)(ws + alloc(4));
  int* rowptr = (int*)(ws + alloc((size_t)(N + 1) * 4));
  float* dinv = (float*)(ws + alloc((size_t)N * 4));
  unsigned* pk = (unsigned*)(ws + alloc((size_t)E * 4));
  unsigned* pk2 = (unsigned*)(ws + alloc((size_t)E * 4));
  int* csr = (int*)(ws + alloc((size_t)E * 4));
  bf16* wct1 = (bf16*)(ws + alloc((size_t)384 * 192 * 2));
  bf16* wct2 = (bf16*)(ws + alloc((size_t)384 * 128 * 2));
  bf16* xp = (bf16*)(ws + alloc((size_t)N * 192 * 2));
  bf16* H = xp;  // h reuses xp (dead after gemm1)
  bf16* U0 = (bf16*)(ws + alloc((size_t)N * 128 * 2));
  bf16* U1 = (bf16*)(ws + alloc((size_t)N * 128 * 2));
  u8* G0 = (u8*)(ws + alloc((size_t)NSLICE * SLICE_STRIDE));
  u8* G1 = (u8*)(ws + alloc((size_t)NSLICE * SLICE_STRIDE));
  f32x2* zpart = (f32x2*)(ws + alloc((size_t)NSLICE * N * 8));
  (void)ws_size;

  hipMemsetAsync(flag, 0, 4, stream);
  detect_k<<<256, 256, 0, stream>>>(ei, flag);

  // ---- bucket-sort CSR + degree ----
  hist_k<<<NBLK, 256, 0, stream>>>(ei, E, flag, gcd, gcs);
  scanA_k<<<nChunkS, 256, 0, stream>>>(gcd, bsum, L);
  scanB_k<<<1, 128, 0, stream>>>(bsum, totald, nChunkS);
  scanC_k<<<nChunkS, 256, 0, stream>>>(gcd, bsum, gcd, L);
  scanA_k<<<nChunkS, 256, 0, stream>>>(gcs, bsum, L);
  scanB_k<<<1, 128, 0, stream>>>(bsum, totals, nChunkS);
  scanC_k<<<nChunkS, 256, 0, stream>>>(gcs, bsum, gcs, L);
  scat2_k<<<NBLK, 256, 0, stream>>>(ei, E, flag, gcd, gcs, pk, pk2);
  fin_dst_k<<<NB, 256, 0, stream>>>(pk, gcd, totald, rowptr, csr);
  fin_src_k<<<NB, 256, 0, stream>>>(pk2, gcs, totals, dinv);

  zero_pads_k<<<1, 256, 0, stream>>>(G0, G1);
  pad_x_k<<<cdiv(N * 192, 256), 256, 0, stream>>>(x, xp);
  build_wct_k<<<cdiv(384 * 192, 256), 256, 0, stream>>>(W1, wct1, F_IN, 192);
  build_wct_k<<<cdiv(384 * 128, 256), 256, 0, stream>>>(W2, wct2, 128, 128);

  const int gm = cdiv(N, 128);
  const int pgrid = (N / 4) * NSLICE;  // 100000 blocks; bid = g*4 + s
  // layer 1: Y0 -> U0 (bf16), Y1 -> U1 (bf16), Y2 -> G0 (fp8 sliced, dinv-scaled)
  gemm3_k<<<dim3(gm, 3), 256, 0, stream>>>(xp, 192, wct1, 192, U0, U1, G0, dinv, N);
  // A1 sliced fp8 = dinv*(P(Y2)+Y1): gather G0, add U1 -> G1
  prop_k<0><<<pgrid, 256, 0, stream>>>(rowptr, csr, G0, dinv, U1, nullptr, nullptr,
                                       G1, nullptr, nullptr);
  // h = relu(P(A1)+Y0+b1): gather G1, add U0 -> H (bf16 row-major)
  prop_k<1><<<pgrid, 256, 0, stream>>>(rowptr, csr, G1, dinv, U0, b1, nullptr,
                                       nullptr, H, nullptr);
  // layer 2 from h: Z0 -> U1, Z1 -> U0, Z2 -> G0 (fp8 sliced)
  gemm3_k<<<dim3(gm, 3), 256, 0, stream>>>(H, 128, wct2, 128, U1, U0, G0, dinv, N);
  // A2 sliced fp8 = dinv*(P(Z2)+Z1): gather G0, add U0 -> G1
  prop_k<0><<<pgrid, 256, 0, stream>>>(rowptr, csr, G0, dinv, U0, nullptr, nullptr,
                                       G1, nullptr, nullptr);
  // zpart from gather of G1
  prop_k<2><<<pgrid, 256, 0, stream>>>(rowptr, csr, G1, dinv, nullptr, nullptr, Wl,
                                       nullptr, nullptr, zpart);
  // logits
  logits_k<<<N / 4, 256, 0, stream>>>(U1, H, b2, Wl, bl, zpart, outp);

  copy_edges_k<<<cdiv(2 * E, 256), 256, 0, stream>>>(ei, flag, outp + (size_t)2 * N, 2 * E);
}

// Round 14
// 523.810 us; speedup vs baseline: 1.6878x; 1.6410x over previous
//
#include <hip/hip_runtime.h>
#include <stdint.h>

typedef __bf16 bf16;
typedef unsigned char u8;
typedef __attribute__((ext_vector_type(8))) __bf16 bf16x8;
typedef __attribute__((ext_vector_type(4))) float f32x4;
typedef __attribute__((ext_vector_type(2))) float f32x2;

#define N_NODES 100000
#define F_IN 165
#define NB 391     // coarse buckets of 256 nodes
#define NBLK 320   // blocks in bucket passes

static inline int cdiv(int a, int b) { return (a + b - 1) / b; }

__device__ __forceinline__ float bfu(unsigned hw) {
  union { unsigned u; float f; } v; v.u = hw << 16; return v.f;
}
__device__ __forceinline__ unsigned packbf2(float a, float b) {
  bf16 x = (bf16)a, y = (bf16)b;
  unsigned short sx = __builtin_bit_cast(unsigned short, x);
  unsigned short sy = __builtin_bit_cast(unsigned short, y);
  return (unsigned)sx | ((unsigned)sy << 16);
}
__device__ __forceinline__ unsigned pk_fp8x4(float a, float b, float c, float d) {
  int v = 0;
  v = __builtin_amdgcn_cvt_pk_fp8_f32(a, b, v, false);
  v = __builtin_amdgcn_cvt_pk_fp8_f32(c, d, v, true);
  return (unsigned)v;
}
__device__ __forceinline__ u8 f32_to_fp8(float v) {
  int t = __builtin_amdgcn_cvt_pk_fp8_f32(v, 0.f, 0, false);
  return (u8)(t & 0xff);
}

__device__ __forceinline__ void async16(const bf16* g, const bf16* l) {
  __builtin_amdgcn_global_load_lds(
      (const __attribute__((address_space(1))) void*)g,
      (__attribute__((address_space(3))) void*)l, 16, 0, 0);
}

// ---------------- edge dtype detection ----------------
__global__ void detect_k(const int* __restrict__ ei32, int* __restrict__ flag) {
  int i = blockIdx.x * 256 + threadIdx.x;
  int v = ei32[2 * i + 1];
  if (v != 0) atomicOr(flag, 1);
}

// ---------------- bucket-sort preprocessing (LDS atomics only) ------

__global__ __launch_bounds__(256) void hist_k(const int* __restrict__ ei, int E,
                                              const int* __restrict__ flag,
                                              int* __restrict__ gcd, int* __restrict__ gcs) {
  __shared__ int hd[NB], hs[NB];
  int b = blockIdx.x, t = threadIdx.x;
  for (int i = t; i < NB; i += 256) { hd[i] = 0; hs[i] = 0; }
  __syncthreads();
  int sh = (*flag) ? 0 : 1;
  int CH = (E + NBLK - 1) / NBLK;
  int lo = b * CH, hi = min(E, lo + CH);
  for (int e = lo + t; e < hi; e += 256) {
    int s = ei[(size_t)e << sh];
    int d = ei[(size_t)(E + e) << sh];
    if ((unsigned)s < (unsigned)N_NODES && (unsigned)d < (unsigned)N_NODES && s != d) {
      atomicAdd(&hd[d >> 8], 1);
      atomicAdd(&hs[s >> 8], 1);
    }
  }
  __syncthreads();
  for (int i = t; i < NB; i += 256) {
    gcd[i * NBLK + b] = hd[i];
    gcs[i * NBLK + b] = hs[i];
  }
}

__global__ __launch_bounds__(256) void scat2_k(const int* __restrict__ ei, int E,
                                               const int* __restrict__ flag,
                                               const int* __restrict__ ofd,
                                               const int* __restrict__ ofs,
                                               unsigned* __restrict__ pk,
                                               unsigned* __restrict__ pk2) {
  __shared__ int based[NB], bases[NB];
  int b = blockIdx.x, t = threadIdx.x;
  for (int i = t; i < NB; i += 256) {
    based[i] = ofd[i * NBLK + b];
    bases[i] = ofs[i * NBLK + b];
  }
  __syncthreads();
  int sh = (*flag) ? 0 : 1;
  int CH = (E + NBLK - 1) / NBLK;
  int lo = b * CH, hi = min(E, lo + CH);
  for (int e = lo + t; e < hi; e += 256) {
    int s = ei[(size_t)e << sh];
    int d = ei[(size_t)(E + e) << sh];
    if ((unsigned)s < (unsigned)N_NODES && (unsigned)d < (unsigned)N_NODES && s != d) {
      int pd = atomicAdd(&based[d >> 8], 1);
      pk[pd] = ((unsigned)(d & 255) << 24) | (unsigned)s;
      int ps = atomicAdd(&bases[s >> 8], 1);
      pk2[ps] = (unsigned)s;
    }
  }
}

__global__ __launch_bounds__(256) void fin_dst_k(const unsigned* __restrict__ pk,
                                                 const int* __restrict__ ofd,
                                                 const int* __restrict__ totald,
                                                 int* __restrict__ rowptr,
                                                 int* __restrict__ csr) {
  __shared__ int fh[256], fb[256];
  int b = blockIdx.x, t = threadIdx.x;
  int lo = ofd[b * NBLK];
  int hi = (b == NB - 1) ? *totald : ofd[(b + 1) * NBLK];
  fh[t] = 0;
  __syncthreads();
  for (int i = lo + t; i < hi; i += 256) atomicAdd(&fh[pk[i] >> 24], 1);
  __syncthreads();
  fb[t] = fh[t];
  __syncthreads();
  for (int offv = 1; offv < 256; offv <<= 1) {
    int x = (t >= offv) ? fb[t - offv] : 0;
    __syncthreads();
    fb[t] += x;
    __syncthreads();
  }
  int excl = fb[t] - fh[t];
  int node = b * 256 + t;
  if (node <= N_NODES) rowptr[node] = lo + excl;
  __syncthreads();
  fb[t] = lo + excl;
  __syncthreads();
  for (int i = lo + t; i < hi; i += 256) {
    unsigned v = pk[i];
    int pos = atomicAdd(&fb[v >> 24], 1);
    csr[pos] = (int)(v & 0xFFFFFFu);
  }
}

__global__ __launch_bounds__(256) void fin_src_k(const unsigned* __restrict__ pk2,
                                                 const int* __restrict__ ofs,
                                                 const int* __restrict__ totals,
                                                 float* __restrict__ dinv) {
  __shared__ int fh[256];
  int b = blockIdx.x, t = threadIdx.x;
  int lo = ofs[b * NBLK];
  int hi = (b == NB - 1) ? *totals : ofs[(b + 1) * NBLK];
  fh[t] = 0;
  __syncthreads();
  for (int i = lo + t; i < hi; i += 256) atomicAdd(&fh[pk2[i] & 255], 1);
  __syncthreads();
  int node = b * 256 + t;
  if (node < N_NODES) {
    int dg = fh[t];
    dinv[node] = dg > 0 ? rsqrtf((float)dg) : 0.f;
  }
}

// ---------------- scans ----------------

__global__ void scanA_k(const int* __restrict__ cnt, int* __restrict__ bsum, int nElem) {
  __shared__ int s[256];
  int b = blockIdx.x, t = threadIdx.x;
  int base = b * 1024;
  int sum = 0;
  for (int i = t; i < 1024; i += 256) {
    int idx = base + i;
    sum += (idx < nElem) ? cnt[idx] : 0;
  }
  s[t] = sum; __syncthreads();
  for (int off = 128; off > 0; off >>= 1) {
    if (t < off) s[t] += s[t + off];
    __syncthreads();
  }
  if (t == 0) bsum[b] = s[0];
}

__global__ void scanB_k(int* __restrict__ bsum, int* __restrict__ totalOut, int nChunk) {
  __shared__ int s[128];
  int t = threadIdx.x;
  int v = (t < nChunk) ? bsum[t] : 0;
  s[t] = v; __syncthreads();
  for (int off = 1; off < 128; off <<= 1) {
    int x = (t >= off) ? s[t - off] : 0;
    __syncthreads();
    s[t] += x;
    __syncthreads();
  }
  int excl = s[t] - v;
  if (t < nChunk) bsum[t] = excl;
  if (t == 127) *totalOut = s[127];
}

__global__ void scanC_k(const int* __restrict__ cnt, const int* __restrict__ bsum,
                        int* __restrict__ outp, int nElem) {
  __shared__ int s[256];
  int b = blockIdx.x, t = threadIdx.x;
  int base = b * 1024 + t * 4;
  int v[4]; int tot = 0;
  for (int i = 0; i < 4; i++) {
    int idx = base + i;
    v[i] = (idx < nElem) ? cnt[idx] : 0;
    tot += v[i];
  }
  s[t] = tot; __syncthreads();
  for (int off = 1; off < 256; off <<= 1) {
    int x = (t >= off) ? s[t - off] : 0;
    __syncthreads();
    s[t] += x;
    __syncthreads();
  }
  int excl = s[t] - tot + bsum[b];
  for (int i = 0; i < 4; i++) {
    int idx = base + i;
    if (idx < nElem) { outp[idx] = excl; excl += v[i]; }
  }
}

// ---------------- weight prep ----------------

// W (float): [3][Fin][128].  out (bf16): [384][Kp] = (W0-W2)^T | W1^T | (2W2)^T
__global__ void build_wct_k(const float* __restrict__ W, bf16* __restrict__ out, int Fin, int Kp) {
  int idx = blockIdx.x * 256 + threadIdx.x;
  if (idx >= 384 * Kp) return;
  int r = idx / Kp, k = idx % Kp;
  int t = r >> 7, j = r & 127;
  float v = 0.f;
  if (k < Fin) {
    if (t == 0)
      v = W[(size_t)k * 128 + j] - W[(size_t)2 * Fin * 128 + (size_t)k * 128 + j];
    else if (t == 1)
      v = W[(size_t)Fin * 128 + (size_t)k * 128 + j];
    else
      v = 2.f * W[(size_t)2 * Fin * 128 + (size_t)k * 128 + j];
  }
  out[(size_t)r * Kp + k] = (bf16)v;
}

// layer-2 collapsed weights: wlc[f][6] =
//   c0 = ((W0-W2)@Wl)[f] + Wl[f]   (includes residual h@Wl)
//   c1 = (W1@Wl)[f]
//   c2 = ((2W2)@Wl)[f]
__global__ void build_wlc_k(const float* __restrict__ W2, const float* __restrict__ Wl,
                            float* __restrict__ wlc) {
  int f = threadIdx.x;  // 128
  float c00 = 0, c01 = 0, c10 = 0, c11 = 0, c20 = 0, c21 = 0;
  for (int k = 0; k < 128; k++) {
    float w0 = W2[(size_t)f * 128 + k];
    float w1 = W2[(size_t)128 * 128 + f * 128 + k];
    float w2 = W2[(size_t)2 * 128 * 128 + f * 128 + k];
    float l0 = Wl[k * 2], l1 = Wl[k * 2 + 1];
    c00 += (w0 - w2) * l0; c01 += (w0 - w2) * l1;
    c10 += w1 * l0;        c11 += w1 * l1;
    c20 += 2.f * w2 * l0;  c21 += 2.f * w2 * l1;
  }
  c00 += Wl[f * 2]; c01 += Wl[f * 2 + 1];
  wlc[f * 6 + 0] = c00; wlc[f * 6 + 1] = c01;
  wlc[f * 6 + 2] = c10; wlc[f * 6 + 3] = c11;
  wlc[f * 6 + 4] = c20; wlc[f * 6 + 5] = c21;
}

// cc = b2 @ Wl + bl
__global__ void const_k(const float* __restrict__ b2, const float* __restrict__ Wl,
                        const float* __restrict__ bl, float* __restrict__ cc) {
  int c = threadIdx.x;  // 64
  float p0 = b2[2 * c] * Wl[(2 * c) * 2] + b2[2 * c + 1] * Wl[(2 * c + 1) * 2];
  float p1 = b2[2 * c] * Wl[(2 * c) * 2 + 1] + b2[2 * c + 1] * Wl[(2 * c + 1) * 2 + 1];
#pragma unroll
  for (int off = 32; off > 0; off >>= 1) {
    p0 += __shfl_down(p0, off);
    p1 += __shfl_down(p1, off);
  }
  if (c == 0) { cc[0] = p0 + bl[0]; cc[1] = p1 + bl[1]; }
}

__global__ void pad_x_k(const float* __restrict__ x, bf16* __restrict__ xp) {
  int idx = blockIdx.x * 256 + threadIdx.x;
  if (idx >= N_NODES * 192) return;
  int n = idx / 192, k = idx % 192;
  xp[idx] = (k < F_IN) ? (bf16)x[(size_t)n * F_IN + k] : (bf16)0.f;
}

// zero gather pad rows (node N_NODES) of G0/G1 fp8 buffers
__global__ void zero_pads_k(u8* __restrict__ g0, u8* __restrict__ g1) {
  int t = threadIdx.x;  // 128
  g0[(size_t)N_NODES * 128 + t] = 0;
  g1[(size_t)N_NODES * 128 + t] = 0;
}

// ---------------- GEMM: y=0,1 -> bf16; y=2 -> fp8(dinv[row]*val) row-major ----

__global__ __launch_bounds__(256) void gemm3_k(const bf16* __restrict__ A, int lda,
                                               const bf16* __restrict__ Bt, int K,
                                               bf16* __restrict__ C0, bf16* __restrict__ C1,
                                               u8* __restrict__ C2g,
                                               const float* __restrict__ dinv, int M) {
  __shared__ __align__(16) bf16 As[128 * 32];
  __shared__ __align__(16) bf16 Bs[128 * 32];
  const int tid = threadIdx.x;
  const int w = tid >> 6, l = tid & 63;
  const int mBase = blockIdx.x * 128;
  const int nb = blockIdx.y * 128;
  const int wm = (w >> 1) * 64, wn = (w & 1) * 64;
  const int lr = l & 15, lq = l >> 4;
  f32x4 acc[4][4] = {};
  for (int k0 = 0; k0 < K; k0 += 32) {
#pragma unroll
    for (int p = 0; p < 2; ++p) {
      int q = w * 2 + p;
      int row = q * 16 + (l >> 2);
      int seg = (l & 3) * 8;
      int ar = mBase + row; if (ar > M - 1) ar = M - 1;
      async16(A + (size_t)ar * lda + k0 + seg, &As[q * 512]);
      async16(Bt + (size_t)(nb + row) * K + k0 + seg, &Bs[q * 512]);
    }
    __syncthreads();
    bf16x8 a[4], b[4];
#pragma unroll
    for (int i = 0; i < 4; i++) a[i] = *(const bf16x8*)&As[(wm + i * 16 + lr) * 32 + lq * 8];
#pragma unroll
    for (int j = 0; j < 4; j++) b[j] = *(const bf16x8*)&Bs[(wn + j * 16 + lr) * 32 + lq * 8];
#pragma unroll
    for (int i = 0; i < 4; i++)
#pragma unroll
      for (int j = 0; j < 4; j++)
        acc[i][j] = __builtin_amdgcn_mfma_f32_16x16x32_bf16(a[i], b[j], acc[i][j], 0, 0, 0);
    __syncthreads();
  }
  if (blockIdx.y == 2) {
#pragma unroll
    for (int i = 0; i < 4; i++) {
#pragma unroll
      for (int r = 0; r < 4; r++) {
        int row = mBase + wm + i * 16 + lq * 4 + r;
        if (row < M) {
          float dv = dinv[row];
#pragma unroll
          for (int j = 0; j < 4; j++) {
            int col = wn + j * 16 + lr;
            C2g[(size_t)row * 128 + col] = f32_to_fp8(dv * acc[i][j][r]);
          }
        }
      }
    }
  } else {
    bf16* __restrict__ C = blockIdx.y ? C1 : C0;
#pragma unroll
    for (int i = 0; i < 4; i++) {
#pragma unroll
      for (int r = 0; r < 4; r++) {
        int row = mBase + wm + i * 16 + lq * 4 + r;
        if (row < M) {
#pragma unroll
          for (int j = 0; j < 4; j++) {
            int col = wn + j * 16 + lr;
            C[(size_t)row * 128 + col] = (bf16)acc[i][j][r];
          }
        }
      }
    }
  }
}

// ---------------- full-width sparse propagation (R11 structure) ----------------
// One wave per node; half-wave per edge slot; 16 edges per loop body.
// MODE 0: t = -dn*sum + addA; write fp8(dn*t) -> out8
// MODE 1: t = relu(-dn*sum + addA + bias); write bf16 -> outb
template <int MODE>
__global__ __launch_bounds__(256) void prop_k(const int* __restrict__ rowptr,
                                              const int* __restrict__ csr,
                                              const u8* __restrict__ g8,
                                              const float* __restrict__ dinv,
                                              const bf16* __restrict__ addA,
                                              const float* __restrict__ bias,
                                              u8* __restrict__ out8,
                                              bf16* __restrict__ outb) {
  const int n = blockIdx.x * 4 + (threadIdx.x >> 6);
  const int c = threadIdx.x & 63;
  const int half = c >> 5, lc = c & 31;
  const int beg = rowptr[n], end = rowptr[n + 1];
  const u8* __restrict__ gl = g8 + lc * 4;

  float a0 = 0.f, a1 = 0.f, a2 = 0.f, a3 = 0.f;
  for (int e0 = beg; e0 < end; e0 += 16) {
    int sidx[8];
    unsigned g[8];
#pragma unroll
    for (int k = 0; k < 8; k++) {
      int idx = e0 + 2 * k + half;
      sidx[k] = (idx < end) ? csr[idx] : N_NODES;  // pad row = zeros
    }
#pragma unroll
    for (int k = 0; k < 8; k++) g[k] = *(const unsigned*)(gl + (size_t)sidx[k] * 128);
#pragma unroll
    for (int k = 0; k < 8; k++) {
      auto lo = __builtin_amdgcn_cvt_pk_f32_fp8((int)g[k], false);
      auto hi = __builtin_amdgcn_cvt_pk_f32_fp8((int)g[k], true);
      a0 += lo[0]; a1 += lo[1]; a2 += hi[0]; a3 += hi[1];
    }
  }
  a0 += __shfl_down(a0, 32);
  a1 += __shfl_down(a1, 32);
  a2 += __shfl_down(a2, 32);
  a3 += __shfl_down(a3, 32);
  if (half != 0) return;
  const float dn = dinv[n];
  uint2 ua = *(const uint2*)(addA + (size_t)n * 128 + lc * 4);
  float t0 = -dn * a0 + bfu(ua.x & 0xffffu);
  float t1 = -dn * a1 + bfu(ua.x >> 16);
  float t2 = -dn * a2 + bfu(ua.y & 0xffffu);
  float t3 = -dn * a3 + bfu(ua.y >> 16);
  if (MODE == 1) {
    t0 = fmaxf(t0 + bias[4 * lc + 0], 0.f);
    t1 = fmaxf(t1 + bias[4 * lc + 1], 0.f);
    t2 = fmaxf(t2 + bias[4 * lc + 2], 0.f);
    t3 = fmaxf(t3 + bias[4 * lc + 3], 0.f);
    uint2 st;
    st.x = packbf2(t0, t1);
    st.y = packbf2(t2, t3);
    *(uint2*)(outb + (size_t)n * 128 + lc * 4) = st;
  } else {
    *(unsigned*)(out8 + (size_t)n * 128 + lc * 4) =
        pk_fp8x4(dn * t0, dn * t1, dn * t2, dn * t3);
  }
}

// ---------------- layer-2 collapse: V[n][6] = h[n] @ wlc ----------------
// V0 = h@c0, V1 = h@c1, V2s = dinv[n]*(h@c2)
__global__ __launch_bounds__(256) void gemv6_k(const bf16* __restrict__ H,
                                               const float* __restrict__ wlc,
                                               const float* __restrict__ dinv,
                                               f32x2* __restrict__ V0,
                                               f32x2* __restrict__ V1,
                                               f32x2* __restrict__ V2s) {
  int n = blockIdx.x * 4 + (threadIdx.x >> 6);
  int c = threadIdx.x & 63;
  unsigned u = *(const unsigned*)(H + (size_t)n * 128 + 2 * c);
  float h0 = bfu(u & 0xffffu), h1 = bfu(u >> 16);
  const float* w0 = wlc + (2 * c) * 6;
  const float* w1 = wlc + (2 * c + 1) * 6;
  float p[6];
#pragma unroll
  for (int i = 0; i < 6; i++) p[i] = h0 * w0[i] + h1 * w1[i];
#pragma unroll
  for (int off = 32; off > 0; off >>= 1)
#pragma unroll
    for (int i = 0; i < 6; i++) p[i] += __shfl_down(p[i], off);
  if (c == 0) {
    float dn = dinv[n];
    f32x2 a, b, d;
    a.x = p[0]; a.y = p[1];
    b.x = p[2]; b.y = p[3];
    d.x = dn * p[4]; d.y = dn * p[5];
    V0[n] = a; V1[n] = b; V2s[n] = d;
  }
}

// tiny 2-feature props.
// MODE 0: tW[n] = dn * (-dn * sum(V2s[src]) + V1[n])
// MODE 1: z = -dn * sum(tW[src]) + V0[n] + cc; logits = log_softmax(z)
template <int MODE>
__global__ __launch_bounds__(256) void propT_k(const int* __restrict__ rowptr,
                                               const int* __restrict__ csr,
                                               const f32x2* __restrict__ gsrc,
                                               const float* __restrict__ dinv,
                                               const f32x2* __restrict__ addv,
                                               const float* __restrict__ cc,
                                               f32x2* __restrict__ outv,
                                               float* __restrict__ fout) {
  int n = blockIdx.x * 4 + (threadIdx.x >> 6);
  int l = threadIdx.x & 63;
  int beg = rowptr[n], end = rowptr[n + 1];
  float s0 = 0.f, s1 = 0.f;
  for (int idx = beg + l; idx < end; idx += 64) {
    f32x2 v = gsrc[csr[idx]];
    s0 += v.x;
    s1 += v.y;
  }
#pragma unroll
  for (int off = 32; off > 0; off >>= 1) {
    s0 += __shfl_down(s0, off);
    s1 += __shfl_down(s1, off);
  }
  if (l != 0) return;
  float dn = dinv[n];
  f32x2 av = addv[n];
  if (MODE == 0) {
    f32x2 t;
    t.x = dn * (-dn * s0 + av.x);
    t.y = dn * (-dn * s1 + av.y);
    outv[n] = t;
  } else {
    float z0 = -dn * s0 + av.x + cc[0];
    float z1 = -dn * s1 + av.y + cc[1];
    float m = fmaxf(z0, z1);
    float lse = m + logf(expf(z0 - m) + expf(z1 - m));
    fout[(size_t)n * 2 + 0] = z0 - lse;
    fout[(size_t)n * 2 + 1] = z1 - lse;
  }
}

// edges -> float32 output region
__global__ void copy_edges_k(const int* __restrict__ ei, const int* __restrict__ flag,
                             float* __restrict__ out, int n) {
  int i = blockIdx.x * 256 + threadIdx.x;
  if (i >= n) return;
  int sh = (*flag) ? 0 : 1;
  out[i] = (float)ei[(size_t)i << sh];
}

// ---------------- launch ----------------

extern "C" void kernel_launch(void* const* d_in, const int* in_sizes, int n_in,
                              void* d_out, int out_size, void* d_ws, size_t ws_size,
                              hipStream_t stream) {
  const float* x = (const float*)d_in[0];
  const int* ei = (const int*)d_in[1];
  const float* W1 = (const float*)d_in[2];
  const float* b1 = (const float*)d_in[3];
  const float* W2 = (const float*)d_in[4];
  const float* b2 = (const float*)d_in[5];
  const float* Wl = (const float*)d_in[6];
  const float* bl = (const float*)d_in[7];
  float* outp = (float*)d_out;

  const int N = N_NODES;
  const int E = in_sizes[1] / 2;
  const int L = NB * NBLK;
  const int nChunkS = cdiv(L, 1024);

  char* ws = (char*)d_ws;
  size_t off = 0;
  auto alloc = [&](size_t bytes) {
    off = (off + 255) & ~(size_t)255;
    size_t o = off;
    off += bytes;
    return o;
  };
  int* flag = (int*)(ws + alloc(4));
  int* gcd = (int*)(ws + alloc((size_t)L * 4));
  int* gcs = (int*)(ws + alloc((size_t)L * 4));
  int* bsum = (int*)(ws + alloc(512));
  int* totald = (int*)(ws + alloc(4));
  int* totals = (int*)(ws + alloc(4));
  int* rowptr = (int*)(ws + alloc((size_t)(N + 1) * 4));
  float* dinv = (float*)(ws + alloc((size_t)N * 4));
  unsigned* pk = (unsigned*)(ws + alloc((size_t)E * 4));
  unsigned* pk2 = (unsigned*)(ws + alloc((size_t)E * 4));
  int* csr = (int*)(ws + alloc((size_t)E * 4));
  bf16* wct1 = (bf16*)(ws + alloc((size_t)384 * 192 * 2));
  float* wlc = (float*)(ws + alloc((size_t)128 * 6 * 4));
  float* cc = (float*)(ws + alloc(8));
  bf16* xp = (bf16*)(ws + alloc((size_t)N * 192 * 2));
  bf16* H = xp;  // h reuses xp (dead after gemm1)
  bf16* U0 = (bf16*)(ws + alloc((size_t)N * 128 * 2));
  bf16* U1 = (bf16*)(ws + alloc((size_t)N * 128 * 2));
  u8* G0 = (u8*)(ws + alloc((size_t)(N + 1) * 128));
  u8* G1 = (u8*)(ws + alloc((size_t)(N + 1) * 128));
  f32x2* V0 = (f32x2*)(ws + alloc((size_t)N * 8));
  f32x2* V1 = (f32x2*)(ws + alloc((size_t)N * 8));
  f32x2* V2s = (f32x2*)(ws + alloc((size_t)N * 8));
  f32x2* tW = (f32x2*)(ws + alloc((size_t)N * 8));
  (void)ws_size;

  hipMemsetAsync(flag, 0, 4, stream);
  detect_k<<<256, 256, 0, stream>>>(ei, flag);

  // ---- bucket-sort CSR + degree ----
  hist_k<<<NBLK, 256, 0, stream>>>(ei, E, flag, gcd, gcs);
  scanA_k<<<nChunkS, 256, 0, stream>>>(gcd, bsum, L);
  scanB_k<<<1, 128, 0, stream>>>(bsum, totald, nChunkS);
  scanC_k<<<nChunkS, 256, 0, stream>>>(gcd, bsum, gcd, L);
  scanA_k<<<nChunkS, 256, 0, stream>>>(gcs, bsum, L);
  scanB_k<<<1, 128, 0, stream>>>(bsum, totals, nChunkS);
  scanC_k<<<nChunkS, 256, 0, stream>>>(gcs, bsum, gcs, L);
  scat2_k<<<NBLK, 256, 0, stream>>>(ei, E, flag, gcd, gcs, pk, pk2);
  fin_dst_k<<<NB, 256, 0, stream>>>(pk, gcd, totald, rowptr, csr);
  fin_src_k<<<NB, 256, 0, stream>>>(pk2, gcs, totals, dinv);

  zero_pads_k<<<1, 128, 0, stream>>>(G0, G1);
  pad_x_k<<<cdiv(N * 192, 256), 256, 0, stream>>>(x, xp);
  build_wct_k<<<cdiv(384 * 192, 256), 256, 0, stream>>>(W1, wct1, F_IN, 192);
  build_wlc_k<<<1, 128, 0, stream>>>(W2, Wl, wlc);
  const_k<<<1, 64, 0, stream>>>(b2, Wl, bl, cc);

  const int gm = cdiv(N, 128);
  // layer 1: Y0 -> U0 (bf16), Y1 -> U1 (bf16), Y2 -> G0 (fp8, dinv-scaled)
  gemm3_k<<<dim3(gm, 3), 256, 0, stream>>>(xp, 192, wct1, 192, U0, U1, G0, dinv, N);
  // A1 (fp8, dinv-scaled) = dinv*(P(Y2)+Y1): gather G0, add U1 -> G1
  prop_k<0><<<N / 4, 256, 0, stream>>>(rowptr, csr, G0, dinv, U1, nullptr, G1, nullptr);
  // h = relu(P(A1)+Y0+b1): gather G1, add U0 -> H (bf16)
  prop_k<1><<<N / 4, 256, 0, stream>>>(rowptr, csr, G1, dinv, U0, b1, nullptr, H);
  // layer 2 collapsed to 2 dims: V from h
  gemv6_k<<<N / 4, 256, 0, stream>>>(H, wlc, dinv, V0, V1, V2s);
  // tW = dinv * (P(v2) + v1)
  propT_k<0><<<N / 4, 256, 0, stream>>>(rowptr, csr, V2s, dinv, V1, nullptr, tW, nullptr);
  // logits = log_softmax(P(t) + v0 + cc)
  propT_k<1><<<N / 4, 256, 0, stream>>>(rowptr, csr, tW, dinv, V0, cc, nullptr, outp);

  copy_edges_k<<<cdiv(2 * E, 256), 256, 0, stream>>>(ei, flag, outp + (size_t)2 * N, 2 * E);
}

// Round 15
// 501.530 us; speedup vs baseline: 1.7628x; 1.0444x over previous
//
#include <hip/hip_runtime.h>
#include <stdint.h>

typedef __bf16 bf16;
typedef unsigned char u8;
typedef __attribute__((ext_vector_type(8))) __bf16 bf16x8;
typedef __attribute__((ext_vector_type(4))) float f32x4;
typedef __attribute__((ext_vector_type(2))) float f32x2;

#define N_NODES 100000
#define F_IN 165
#define NB 391     // coarse buckets of 256 nodes
#define NBLK 320   // blocks in bucket passes

static inline int cdiv(int a, int b) { return (a + b - 1) / b; }

__device__ __forceinline__ float bfu(unsigned hw) {
  union { unsigned u; float f; } v; v.u = hw << 16; return v.f;
}
__device__ __forceinline__ unsigned packbf2(float a, float b) {
  bf16 x = (bf16)a, y = (bf16)b;
  unsigned short sx = __builtin_bit_cast(unsigned short, x);
  unsigned short sy = __builtin_bit_cast(unsigned short, y);
  return (unsigned)sx | ((unsigned)sy << 16);
}
__device__ __forceinline__ u8 f32_to_fp8(float v) {
  int t = __builtin_amdgcn_cvt_pk_fp8_f32(v, 0.f, 0, false);
  return (u8)(t & 0xff);
}

__device__ __forceinline__ void async16(const bf16* g, const bf16* l) {
  __builtin_amdgcn_global_load_lds(
      (const __attribute__((address_space(1))) void*)g,
      (__attribute__((address_space(3))) void*)l, 16, 0, 0);
}

// ---------------- edge dtype detection ----------------
__global__ void detect_k(const int* __restrict__ ei32, int* __restrict__ flag) {
  int i = blockIdx.x * 256 + threadIdx.x;
  int v = ei32[2 * i + 1];
  if (v != 0) atomicOr(flag, 1);
}

// ---------------- bucket-sort preprocessing (LDS atomics only) ------

__global__ __launch_bounds__(256) void hist_k(const int* __restrict__ ei, int E,
                                              const int* __restrict__ flag,
                                              int* __restrict__ gcd, int* __restrict__ gcs) {
  __shared__ int hd[NB], hs[NB];
  int b = blockIdx.x, t = threadIdx.x;
  for (int i = t; i < NB; i += 256) { hd[i] = 0; hs[i] = 0; }
  __syncthreads();
  int sh = (*flag) ? 0 : 1;
  int CH = (E + NBLK - 1) / NBLK;
  int lo = b * CH, hi = min(E, lo + CH);
  for (int e = lo + t; e < hi; e += 256) {
    int s = ei[(size_t)e << sh];
    int d = ei[(size_t)(E + e) << sh];
    if ((unsigned)s < (unsigned)N_NODES && (unsigned)d < (unsigned)N_NODES && s != d) {
      atomicAdd(&hd[d >> 8], 1);
      atomicAdd(&hs[s >> 8], 1);
    }
  }
  __syncthreads();
  for (int i = t; i < NB; i += 256) {
    gcd[i * NBLK + b] = hd[i];
    gcs[i * NBLK + b] = hs[i];
  }
}

// scatter dst-sorted and src-sorted entries into ONE packed buffer
// (src region offsets already include the dst-region total, via concatenated scan)
__global__ __launch_bounds__(256) void scat2_k(const int* __restrict__ ei, int E,
                                               const int* __restrict__ flag,
                                               const int* __restrict__ ofd,
                                               const int* __restrict__ ofs,
                                               unsigned* __restrict__ pkAll) {
  __shared__ int based[NB], bases[NB];
  int b = blockIdx.x, t = threadIdx.x;
  for (int i = t; i < NB; i += 256) {
    based[i] = ofd[i * NBLK + b];
    bases[i] = ofs[i * NBLK + b];
  }
  __syncthreads();
  int sh = (*flag) ? 0 : 1;
  int CH = (E + NBLK - 1) / NBLK;
  int lo = b * CH, hi = min(E, lo + CH);
  for (int e = lo + t; e < hi; e += 256) {
    int s = ei[(size_t)e << sh];
    int d = ei[(size_t)(E + e) << sh];
    if ((unsigned)s < (unsigned)N_NODES && (unsigned)d < (unsigned)N_NODES && s != d) {
      int pd = atomicAdd(&based[d >> 8], 1);
      pkAll[pd] = ((unsigned)(d & 255) << 24) | (unsigned)s;
      int ps = atomicAdd(&bases[s >> 8], 1);
      pkAll[ps] = (unsigned)s;
    }
  }
}

__global__ __launch_bounds__(256) void fin_dst_k(const unsigned* __restrict__ pk,
                                                 const int* __restrict__ ofd,
                                                 const int* __restrict__ totald,
                                                 int* __restrict__ rowptr,
                                                 int* __restrict__ csr) {
  __shared__ int fh[256], fb[256];
  int b = blockIdx.x, t = threadIdx.x;
  int lo = ofd[b * NBLK];
  int hi = (b == NB - 1) ? *totald : ofd[(b + 1) * NBLK];
  fh[t] = 0;
  __syncthreads();
  for (int i = lo + t; i < hi; i += 256) atomicAdd(&fh[pk[i] >> 24], 1);
  __syncthreads();
  fb[t] = fh[t];
  __syncthreads();
  for (int offv = 1; offv < 256; offv <<= 1) {
    int x = (t >= offv) ? fb[t - offv] : 0;
    __syncthreads();
    fb[t] += x;
    __syncthreads();
  }
  int excl = fb[t] - fh[t];
  int node = b * 256 + t;
  if (node <= N_NODES) rowptr[node] = lo + excl;
  __syncthreads();
  fb[t] = lo + excl;
  __syncthreads();
  for (int i = lo + t; i < hi; i += 256) {
    unsigned v = pk[i];
    int pos = atomicAdd(&fb[v >> 24], 1);
    csr[pos] = (int)(v & 0xFFFFFFu);
  }
}

__global__ __launch_bounds__(256) void fin_src_k(const unsigned* __restrict__ pk,
                                                 const int* __restrict__ ofs,
                                                 const int* __restrict__ grand,
                                                 float* __restrict__ dinv) {
  __shared__ int fh[256];
  int b = blockIdx.x, t = threadIdx.x;
  int lo = ofs[b * NBLK];
  int hi = (b == NB - 1) ? *grand : ofs[(b + 1) * NBLK];
  fh[t] = 0;
  __syncthreads();
  for (int i = lo + t; i < hi; i += 256) atomicAdd(&fh[pk[i] & 255], 1);
  __syncthreads();
  int node = b * 256 + t;
  if (node < N_NODES) {
    int dg = fh[t];
    dinv[node] = dg > 0 ? rsqrtf((float)dg) : 0.f;
  }
}

// ---------------- scans (concatenated, nElem up to 256*1024) ----------------

__global__ void scanA_k(const int* __restrict__ cnt, int* __restrict__ bsum, int nElem) {
  __shared__ int s[256];
  int b = blockIdx.x, t = threadIdx.x;
  int base = b * 1024;
  int sum = 0;
  for (int i = t; i < 1024; i += 256) {
    int idx = base + i;
    sum += (idx < nElem) ? cnt[idx] : 0;
  }
  s[t] = sum; __syncthreads();
  for (int off = 128; off > 0; off >>= 1) {
    if (t < off) s[t] += s[t + off];
    __syncthreads();
  }
  if (t == 0) bsum[b] = s[0];
}

__global__ void scanB_k(int* __restrict__ bsum, int* __restrict__ totalOut, int nChunk) {
  __shared__ int s[256];
  int t = threadIdx.x;  // 256
  int v = (t < nChunk) ? bsum[t] : 0;
  s[t] = v; __syncthreads();
  for (int off = 1; off < 256; off <<= 1) {
    int x = (t >= off) ? s[t - off] : 0;
    __syncthreads();
    s[t] += x;
    __syncthreads();
  }
  int excl = s[t] - v;
  if (t < nChunk) bsum[t] = excl;
  if (t == 255) *totalOut = s[255];
}

__global__ void scanC_k(const int* __restrict__ cnt, const int* __restrict__ bsum,
                        int* __restrict__ outp, int nElem) {
  __shared__ int s[256];
  int b = blockIdx.x, t = threadIdx.x;
  int base = b * 1024 + t * 4;
  int v[4]; int tot = 0;
  for (int i = 0; i < 4; i++) {
    int idx = base + i;
    v[i] = (idx < nElem) ? cnt[idx] : 0;
    tot += v[i];
  }
  s[t] = tot; __syncthreads();
  for (int off = 1; off < 256; off <<= 1) {
    int x = (t >= off) ? s[t - off] : 0;
    __syncthreads();
    s[t] += x;
    __syncthreads();
  }
  int excl = s[t] - tot + bsum[b];
  for (int i = 0; i < 4; i++) {
    int idx = base + i;
    if (idx < nElem) { outp[idx] = excl; excl += v[i]; }
  }
}

// ---------------- weight prep ----------------

// W (float): [3][Fin][128].  out (bf16): [384][Kp] = (W0-W2)^T | W1^T | (2W2)^T
__global__ void build_wct_k(const float* __restrict__ W, bf16* __restrict__ out, int Fin, int Kp) {
  int idx = blockIdx.x * 256 + threadIdx.x;
  if (idx >= 384 * Kp) return;
  int r = idx / Kp, k = idx % Kp;
  int t = r >> 7, j = r & 127;
  float v = 0.f;
  if (k < Fin) {
    if (t == 0)
      v = W[(size_t)k * 128 + j] - W[(size_t)2 * Fin * 128 + (size_t)k * 128 + j];
    else if (t == 1)
      v = W[(size_t)Fin * 128 + (size_t)k * 128 + j];
    else
      v = 2.f * W[(size_t)2 * Fin * 128 + (size_t)k * 128 + j];
  }
  out[(size_t)r * Kp + k] = (bf16)v;
}

// fused prep: wlc (t<128), fp4 pad rows (t<32), cc (wave 2)
__global__ void prep_k(const float* __restrict__ W2, const float* __restrict__ Wl,
                       const float* __restrict__ b2, const float* __restrict__ bl,
                       float* __restrict__ wlc, float* __restrict__ cc,
                       u8* __restrict__ g0, u8* __restrict__ g1) {
  int t = threadIdx.x;  // 256
  if (t < 16) ((unsigned*)(g0 + (size_t)N_NODES * 64))[t] = 0;
  else if (t < 32) ((unsigned*)(g1 + (size_t)N_NODES * 64))[t - 16] = 0;
  if (t < 128) {
    int f = t;
    float c00 = 0, c01 = 0, c10 = 0, c11 = 0, c20 = 0, c21 = 0;
    for (int k = 0; k < 128; k++) {
      float w0 = W2[(size_t)f * 128 + k];
      float w1 = W2[(size_t)128 * 128 + f * 128 + k];
      float w2 = W2[(size_t)2 * 128 * 128 + f * 128 + k];
      float l0 = Wl[k * 2], l1 = Wl[k * 2 + 1];
      c00 += (w0 - w2) * l0; c01 += (w0 - w2) * l1;
      c10 += w1 * l0;        c11 += w1 * l1;
      c20 += 2.f * w2 * l0;  c21 += 2.f * w2 * l1;
    }
    c00 += Wl[f * 2]; c01 += Wl[f * 2 + 1];
    wlc[f * 6 + 0] = c00; wlc[f * 6 + 1] = c01;
    wlc[f * 6 + 2] = c10; wlc[f * 6 + 3] = c11;
    wlc[f * 6 + 4] = c20; wlc[f * 6 + 5] = c21;
  } else if (t < 192) {
    int c = t - 128;  // 0..63 within wave 2
    float p0 = b2[2 * c] * Wl[(2 * c) * 2] + b2[2 * c + 1] * Wl[(2 * c + 1) * 2];
    float p1 = b2[2 * c] * Wl[(2 * c) * 2 + 1] + b2[2 * c + 1] * Wl[(2 * c + 1) * 2 + 1];
#pragma unroll
    for (int off = 32; off > 0; off >>= 1) {
      p0 += __shfl_down(p0, off);
      p1 += __shfl_down(p1, off);
    }
    if (c == 0) { cc[0] = p0 + bl[0]; cc[1] = p1 + bl[1]; }
  }
}

// pad x (float [N][165]) -> xp (bf16 [N][192]); 2 features per thread
__global__ void pad_x_k(const float* __restrict__ x, bf16* __restrict__ xp) {
  int idx = blockIdx.x * 256 + threadIdx.x;
  if (idx >= N_NODES * 96) return;
  int n = idx / 96, k = (idx % 96) * 2;
  float a = (k < F_IN) ? x[(size_t)n * F_IN + k] : 0.f;
  float b = (k + 1 < F_IN) ? x[(size_t)n * F_IN + k + 1] : 0.f;
  *(unsigned*)(xp + (size_t)n * 192 + k) = packbf2(a, b);
}

// ---------------- GEMM: y=0,1 -> bf16; y=2 -> fp8(dinv[row]*val) row-major ----

__global__ __launch_bounds__(256) void gemm3_k(const bf16* __restrict__ A, int lda,
                                               const bf16* __restrict__ Bt, int K,
                                               bf16* __restrict__ C0, bf16* __restrict__ C1,
                                               u8* __restrict__ C2g,
                                               const float* __restrict__ dinv, int M) {
  __shared__ __align__(16) bf16 As[128 * 32];
  __shared__ __align__(16) bf16 Bs[128 * 32];
  const int tid = threadIdx.x;
  const int w = tid >> 6, l = tid & 63;
  const int mBase = blockIdx.x * 128;
  const int nb = blockIdx.y * 128;
  const int wm = (w >> 1) * 64, wn = (w & 1) * 64;
  const int lr = l & 15, lq = l >> 4;
  f32x4 acc[4][4] = {};
  for (int k0 = 0; k0 < K; k0 += 32) {
#pragma unroll
    for (int p = 0; p < 2; ++p) {
      int q = w * 2 + p;
      int row = q * 16 + (l >> 2);
      int seg = (l & 3) * 8;
      int ar = mBase + row; if (ar > M - 1) ar = M - 1;
      async16(A + (size_t)ar * lda + k0 + seg, &As[q * 512]);
      async16(Bt + (size_t)(nb + row) * K + k0 + seg, &Bs[q * 512]);
    }
    __syncthreads();
    bf16x8 a[4], b[4];
#pragma unroll
    for (int i = 0; i < 4; i++) a[i] = *(const bf16x8*)&As[(wm + i * 16 + lr) * 32 + lq * 8];
#pragma unroll
    for (int j = 0; j < 4; j++) b[j] = *(const bf16x8*)&Bs[(wn + j * 16 + lr) * 32 + lq * 8];
#pragma unroll
    for (int i = 0; i < 4; i++)
#pragma unroll
      for (int j = 0; j < 4; j++)
        acc[i][j] = __builtin_amdgcn_mfma_f32_16x16x32_bf16(a[i], b[j], acc[i][j], 0, 0, 0);
    __syncthreads();
  }
  if (blockIdx.y == 2) {
#pragma unroll
    for (int i = 0; i < 4; i++) {
#pragma unroll
      for (int r = 0; r < 4; r++) {
        int row = mBase + wm + i * 16 + lq * 4 + r;
        if (row < M) {
          float dv = dinv[row];
#pragma unroll
          for (int j = 0; j < 4; j++) {
            int col = wn + j * 16 + lr;
            C2g[(size_t)row * 128 + col] = f32_to_fp8(dv * acc[i][j][r]);
          }
        }
      }
    }
  } else {
    bf16* __restrict__ C = blockIdx.y ? C1 : C0;
#pragma unroll
    for (int i = 0; i < 4; i++) {
#pragma unroll
      for (int r = 0; r < 4; r++) {
        int row = mBase + wm + i * 16 + lq * 4 + r;
        if (row < M) {
#pragma unroll
          for (int j = 0; j < 4; j++) {
            int col = wn + j * 16 + lr;
            C[(size_t)row * 128 + col] = (bf16)acc[i][j][r];
          }
        }
      }
    }
  }
}

// fp8 row-major [N][128] -> fp4 [N][64B] with x2 prescale
__global__ void cvt48_k(const u8* __restrict__ g8, u8* __restrict__ g4) {
  int i = blockIdx.x * 256 + threadIdx.x;
  if (i >= N_NODES * 16) return;
  int n = i >> 4, j = i & 15;
  uint2 w = *(const uint2*)(g8 + (size_t)n * 128 + j * 8);
  auto a0 = __builtin_amdgcn_cvt_pk_f32_fp8((int)w.x, false);
  auto a1 = __builtin_amdgcn_cvt_pk_f32_fp8((int)w.x, true);
  auto a2 = __builtin_amdgcn_cvt_pk_f32_fp8((int)w.y, false);
  auto a3 = __builtin_amdgcn_cvt_pk_f32_fp8((int)w.y, true);
  unsigned u = 0;
  u = __builtin_amdgcn_cvt_scalef32_pk_fp4_f32(u, 2.f * a0[0], 2.f * a0[1], 1.f, 0);
  u = __builtin_amdgcn_cvt_scalef32_pk_fp4_f32(u, 2.f * a1[0], 2.f * a1[1], 1.f, 1);
  u = __builtin_amdgcn_cvt_scalef32_pk_fp4_f32(u, 2.f * a2[0], 2.f * a2[1], 1.f, 2);
  u = __builtin_amdgcn_cvt_scalef32_pk_fp4_f32(u, 2.f * a3[0], 2.f * a3[1], 1.f, 3);
  *(unsigned*)(g4 + (size_t)n * 64 + j * 4) = u;
}

// ---------------- fp4 sparse propagation ----------------
// Wave = 1 node. Quarter-wave (16 lanes) per edge; lane j covers features 8j..8j+7
// (dword j of the 64B fp4 row). 16 edges per loop body (4 per quarter).
// Tables store fp4(2 * dinv_src * value); consumer multiplies sums by 0.5.
// MODE 0: t = -0.5*dn*S + addA;          write fp4(2*dn*t) -> out4
// MODE 1: h = relu(-0.5*dn*S + addA + bias); fused V = h @ wlc -> V0,V1,V2s
template <int MODE>
__global__ __launch_bounds__(256) void prop_k(const int* __restrict__ rowptr,
                                              const int* __restrict__ csr,
                                              const u8* __restrict__ g4,
                                              const float* __restrict__ dinv,
                                              const bf16* __restrict__ addA,
                                              const float* __restrict__ bias,
                                              const float* __restrict__ wlc,
                                              u8* __restrict__ out4,
                                              f32x2* __restrict__ V0,
                                              f32x2* __restrict__ V1,
                                              f32x2* __restrict__ V2s) {
  const int n = blockIdx.x * 4 + (threadIdx.x >> 6);
  const int lane = threadIdx.x & 63;
  const int qq = lane >> 4, j = lane & 15;
  const int beg = rowptr[n], end = rowptr[n + 1];
  const u8* __restrict__ gl = g4 + j * 4;  // dword j of each row

  float a[8] = {};
  for (int e0 = beg; e0 < end; e0 += 16) {
    int sidx[4];
    unsigned w[4];
#pragma unroll
    for (int u = 0; u < 4; u++) {
      int ii = e0 + 4 * u + qq;
      sidx[u] = (ii < end) ? csr[ii] : N_NODES;  // pad row = zeros
    }
#pragma unroll
    for (int u = 0; u < 4; u++) w[u] = *(const unsigned*)(gl + (size_t)sidx[u] * 64);
#pragma unroll
    for (int u = 0; u < 4; u++) {
      auto f0 = __builtin_amdgcn_cvt_scalef32_pk_f32_fp4(w[u], 1.f, 0);
      auto f1 = __builtin_amdgcn_cvt_scalef32_pk_f32_fp4(w[u], 1.f, 1);
      auto f2 = __builtin_amdgcn_cvt_scalef32_pk_f32_fp4(w[u], 1.f, 2);
      auto f3 = __builtin_amdgcn_cvt_scalef32_pk_f32_fp4(w[u], 1.f, 3);
      a[0] += f0[0]; a[1] += f0[1]; a[2] += f1[0]; a[3] += f1[1];
      a[4] += f2[0]; a[5] += f2[1]; a[6] += f3[0]; a[7] += f3[1];
    }
  }
  // reduce the 4 quarters: lanes 0..15 (qq==0) end up with full sums
#pragma unroll
  for (int off = 32; off >= 16; off >>= 1)
#pragma unroll
    for (int i = 0; i < 8; i++) a[i] += __shfl_down(a[i], off);

  const float dn = dinv[n];
  // per-node additive terms: 8 bf16 at features 8j..8j+7
  uint4 ua = *(const uint4*)(addA + (size_t)n * 128 + j * 8);
  float y[8];
  y[0] = bfu(ua.x & 0xffffu); y[1] = bfu(ua.x >> 16);
  y[2] = bfu(ua.y & 0xffffu); y[3] = bfu(ua.y >> 16);
  y[4] = bfu(ua.z & 0xffffu); y[5] = bfu(ua.z >> 16);
  y[6] = bfu(ua.w & 0xffffu); y[7] = bfu(ua.w >> 16);
  float t[8];
#pragma unroll
  for (int i = 0; i < 8; i++) t[i] = -0.5f * dn * a[i] + y[i];

  if (MODE == 0) {
    if (qq == 0) {
      unsigned u = 0;
      u = __builtin_amdgcn_cvt_scalef32_pk_fp4_f32(u, 2.f * dn * t[0], 2.f * dn * t[1], 1.f, 0);
      u = __builtin_amdgcn_cvt_scalef32_pk_fp4_f32(u, 2.f * dn * t[2], 2.f * dn * t[3], 1.f, 1);
      u = __builtin_amdgcn_cvt_scalef32_pk_fp4_f32(u, 2.f * dn * t[4], 2.f * dn * t[5], 1.f, 2);
      u = __builtin_amdgcn_cvt_scalef32_pk_fp4_f32(u, 2.f * dn * t[6], 2.f * dn * t[7], 1.f, 3);
      *(unsigned*)(out4 + (size_t)n * 64 + j * 4) = u;
    }
  } else {
    // h = relu(t + bias); fused V = h @ wlc  (lanes >=16 compute garbage, discarded)
    float p0 = 0, p1 = 0, p2 = 0, p3 = 0, p4 = 0, p5 = 0;
#pragma unroll
    for (int i = 0; i < 8; i++) {
      int f = 8 * j + i;
      float h = fmaxf(t[i] + bias[f], 0.f);
      const float* wr = wlc + f * 6;
      p0 += h * wr[0]; p1 += h * wr[1]; p2 += h * wr[2];
      p3 += h * wr[3]; p4 += h * wr[4]; p5 += h * wr[5];
    }
#pragma unroll
    for (int off = 8; off >= 1; off >>= 1) {
      p0 += __shfl_down(p0, off); p1 += __shfl_down(p1, off);
      p2 += __shfl_down(p2, off); p3 += __shfl_down(p3, off);
      p4 += __shfl_down(p4, off); p5 += __shfl_down(p5, off);
    }
    if (lane == 0) {
      f32x2 v0, v1, v2;
      v0.x = p0; v0.y = p1;
      v1.x = p2; v1.y = p3;
      v2.x = dn * p4; v2.y = dn * p5;
      V0[n] = v0; V1[n] = v1; V2s[n] = v2;
    }
  }
}

// tiny 2-feature props.
// MODE 0: tW[n] = dn * (-dn * sum(V2s[src]) + V1[n])
// MODE 1: z = -dn * sum(tW[src]) + V0[n] + cc; logits = log_softmax(z)
template <int MODE>
__global__ __launch_bounds__(256) void propT_k(const int* __restrict__ rowptr,
                                               const int* __restrict__ csr,
                                               const f32x2* __restrict__ gsrc,
                                               const float* __restrict__ dinv,
                                               const f32x2* __restrict__ addv,
                                               const float* __restrict__ cc,
                                               f32x2* __restrict__ outv,
                                               float* __restrict__ fout) {
  int n = blockIdx.x * 4 + (threadIdx.x >> 6);
  int l = threadIdx.x & 63;
  int beg = rowptr[n], end = rowptr[n + 1];
  float s0 = 0.f, s1 = 0.f;
  for (int idx = beg + l; idx < end; idx += 64) {
    f32x2 v = gsrc[csr[idx]];
    s0 += v.x;
    s1 += v.y;
  }
#pragma unroll
  for (int off = 32; off > 0; off >>= 1) {
    s0 += __shfl_down(s0, off);
    s1 += __shfl_down(s1, off);
  }
  if (l != 0) return;
  float dn = dinv[n];
  f32x2 av = addv[n];
  if (MODE == 0) {
    f32x2 t;
    t.x = dn * (-dn * s0 + av.x);
    t.y = dn * (-dn * s1 + av.y);
    outv[n] = t;
  } else {
    float z0 = -dn * s0 + av.x + cc[0];
    float z1 = -dn * s1 + av.y + cc[1];
    float m = fmaxf(z0, z1);
    float lse = m + logf(expf(z0 - m) + expf(z1 - m));
    fout[(size_t)n * 2 + 0] = z0 - lse;
    fout[(size_t)n * 2 + 1] = z1 - lse;
  }
}

// edges -> float32 output region
__global__ void copy_edges_k(const int* __restrict__ ei, const int* __restrict__ flag,
                             float* __restrict__ out, int n) {
  int i = blockIdx.x * 256 + threadIdx.x;
  if (i >= n) return;
  int sh = (*flag) ? 0 : 1;
  out[i] = (float)ei[(size_t)i << sh];
}

// ---------------- launch ----------------

extern "C" void kernel_launch(void* const* d_in, const int* in_sizes, int n_in,
                              void* d_out, int out_size, void* d_ws, size_t ws_size,
                              hipStream_t stream) {
  const float* x = (const float*)d_in[0];
  const int* ei = (const int*)d_in[1];
  const float* W1 = (const float*)d_in[2];
  const float* b1 = (const float*)d_in[3];
  const float* W2 = (const float*)d_in[4];
  const float* b2 = (const float*)d_in[5];
  const float* Wl = (const float*)d_in[6];
  const float* bl = (const float*)d_in[7];
  float* outp = (float*)d_out;

  const int N = N_NODES;
  const int E = in_sizes[1] / 2;
  const int L = NB * NBLK;          // 125120
  const int L2 = 2 * L;             // concatenated dst||src counts
  const int nChunkS = cdiv(L2, 1024);  // 245 <= 256

  char* ws = (char*)d_ws;
  size_t off = 0;
  auto alloc = [&](size_t bytes) {
    off = (off + 255) & ~(size_t)255;
    size_t o = off;
    off += bytes;
    return o;
  };
  int* flag = (int*)(ws + alloc(4));
  int* gcAll = (int*)(ws + alloc((size_t)L2 * 4));  // gcd | gcs (adjacent!)
  int* bsum = (int*)(ws + alloc(1024));
  int* grand = (int*)(ws + alloc(4));
  int* rowptr = (int*)(ws + alloc((size_t)(N + 1) * 4));
  float* dinv = (float*)(ws + alloc((size_t)N * 4));
  unsigned* pkAll = (unsigned*)(ws + alloc((size_t)2 * E * 4));
  int* csr = (int*)(ws + alloc((size_t)E * 4));
  bf16* wct1 = (bf16*)(ws + alloc((size_t)384 * 192 * 2));
  float* wlc = (float*)(ws + alloc((size_t)128 * 6 * 4));
  float* cc = (float*)(ws + alloc(8));
  bf16* xp = (bf16*)(ws + alloc((size_t)N * 192 * 2));
  bf16* U0 = (bf16*)(ws + alloc((size_t)N * 128 * 2));
  bf16* U1 = (bf16*)(ws + alloc((size_t)N * 128 * 2));
  u8* G8 = (u8*)(ws + alloc((size_t)N * 128));          // fp8 gemm slab-2 out
  u8* G0 = (u8*)(ws + alloc((size_t)(N + 1) * 64));     // fp4 tables
  u8* G1 = (u8*)(ws + alloc((size_t)(N + 1) * 64));
  f32x2* V0 = (f32x2*)(ws + alloc((size_t)N * 8));
  f32x2* V1 = (f32x2*)(ws + alloc((size_t)N * 8));
  f32x2* V2s = (f32x2*)(ws + alloc((size_t)N * 8));
  f32x2* tW = (f32x2*)(ws + alloc((size_t)N * 8));
  (void)ws_size;

  int* gcd = gcAll;
  int* gcs = gcAll + L;

  hipMemsetAsync(flag, 0, 4, stream);
  detect_k<<<256, 256, 0, stream>>>(ei, flag);

  // ---- bucket-sort CSR + degree (one concatenated scan) ----
  hist_k<<<NBLK, 256, 0, stream>>>(ei, E, flag, gcd, gcs);
  scanA_k<<<nChunkS, 256, 0, stream>>>(gcAll, bsum, L2);
  scanB_k<<<1, 256, 0, stream>>>(bsum, grand, nChunkS);
  scanC_k<<<nChunkS, 256, 0, stream>>>(gcAll, bsum, gcAll, L2);
  scat2_k<<<NBLK, 256, 0, stream>>>(ei, E, flag, gcd, gcs, pkAll);
  fin_dst_k<<<NB, 256, 0, stream>>>(pkAll, gcd, gcAll + L, rowptr, csr);
  fin_src_k<<<NB, 256, 0, stream>>>(pkAll, gcs, grand, dinv);

  prep_k<<<1, 256, 0, stream>>>(W2, Wl, b2, bl, wlc, cc, G0, G1);
  pad_x_k<<<cdiv(N * 96, 256), 256, 0, stream>>>(x, xp);
  build_wct_k<<<cdiv(384 * 192, 256), 256, 0, stream>>>(W1, wct1, F_IN, 192);

  const int gm = cdiv(N, 128);
  // layer 1: Y0 -> U0 (bf16), Y1 -> U1 (bf16), Y2 -> G8 (fp8, dinv-scaled)
  gemm3_k<<<dim3(gm, 3), 256, 0, stream>>>(xp, 192, wct1, 192, U0, U1, G8, dinv, N);
  cvt48_k<<<cdiv(N * 16, 256), 256, 0, stream>>>(G8, G0);
  // A1 (fp4) = dinv*(P(Y2)+Y1): gather G0, add U1 -> G1
  prop_k<0><<<N / 4, 256, 0, stream>>>(rowptr, csr, G0, dinv, U1, nullptr, nullptr,
                                       G1, nullptr, nullptr, nullptr);
  // h = relu(P(A1)+Y0+b1) fused with V = h@wlc
  prop_k<1><<<N / 4, 256, 0, stream>>>(rowptr, csr, G1, dinv, U0, b1, wlc,
                                       nullptr, V0, V1, V2s);
  // tW = dinv * (P(v2) + v1)
  propT_k<0><<<N / 4, 256, 0, stream>>>(rowptr, csr, V2s, dinv, V1, nullptr, tW, nullptr);
  // logits = log_softmax(P(t) + v0 + cc)
  propT_k<1><<<N / 4, 256, 0, stream>>>(rowptr, csr, tW, dinv, V0, cc, nullptr, outp);

  copy_edges_k<<<cdiv(2 * E, 256), 256, 0, stream>>>(ei, flag, outp + (size_t)2 * N, 2 * E);
}